// Round 1
// baseline (3548.071 us; speedup 1.0000x reference)
//
#include <hip/hip_runtime.h>
#include <math.h>

#define TOKS 4096          // B*S
#define HS 2048            // hidden size
#define QKV_N 3072         // (16 + 2*4) * 128
#define S_LEN 2048
#define NH 16
#define NKV 4
#define DH 128

// ---------------------------------------------------------------------------
// Generic fp32 GEMM: C = A(MxK) @ B(KxN), all row-major. 64x64 tile, BK=16,
// 256 threads, 4x4 micro-tile per thread.
// ---------------------------------------------------------------------------
__global__ __launch_bounds__(256)
void gemm_f32(const float* __restrict__ A, const float* __restrict__ B,
              float* __restrict__ C, int M, int N, int K) {
  __shared__ float As[16][68];   // [k][m], padded
  __shared__ float Bs[16][68];   // [k][n], padded

  const int t  = threadIdx.x;
  const int tx = t & 15;
  const int ty = t >> 4;
  const int bn = blockIdx.x * 64;
  const int bm = blockIdx.y * 64;

  const int ak  = t & 15;   // k for A-load
  const int am  = t >> 4;   // m base for A-load
  const int bnn = t & 63;   // n for B-load
  const int bk  = t >> 6;   // k base for B-load

  float acc[4][4];
  #pragma unroll
  for (int i = 0; i < 4; ++i)
    #pragma unroll
    for (int j = 0; j < 4; ++j) acc[i][j] = 0.f;

  for (int k0 = 0; k0 < K; k0 += 16) {
    #pragma unroll
    for (int i = 0; i < 4; ++i)
      As[ak][am + 16*i] = A[(size_t)(bm + am + 16*i) * K + (k0 + ak)];
    #pragma unroll
    for (int i = 0; i < 4; ++i)
      Bs[bk + 4*i][bnn] = B[(size_t)(k0 + bk + 4*i) * N + (bn + bnn)];
    __syncthreads();

    #pragma unroll
    for (int kk = 0; kk < 16; ++kk) {
      const float4 av = *(const float4*)&As[kk][ty * 4];
      const float4 bv = *(const float4*)&Bs[kk][tx * 4];
      const float a0[4] = {av.x, av.y, av.z, av.w};
      const float b0[4] = {bv.x, bv.y, bv.z, bv.w};
      #pragma unroll
      for (int i = 0; i < 4; ++i)
        #pragma unroll
        for (int j = 0; j < 4; ++j)
          acc[i][j] += a0[i] * b0[j];
    }
    __syncthreads();
  }

  #pragma unroll
  for (int i = 0; i < 4; ++i) {
    float4 v = make_float4(acc[i][0], acc[i][1], acc[i][2], acc[i][3]);
    *(float4*)&C[(size_t)(bm + ty*4 + i) * N + (bn + tx*4)] = v;
  }
}

// ---------------------------------------------------------------------------
// Fused RMSNorm + RoPE, in place on the qkv buffer. One wave per (token, head
// slot). Slots 0..15 = q heads, 16..19 = k heads. Lane i owns rope pair
// (i, i+64).
// ---------------------------------------------------------------------------
__global__ __launch_bounds__(64)
void norm_rope(float* __restrict__ qkv, const int* __restrict__ positions,
               const float* __restrict__ qw, const float* __restrict__ kw) {
  const int tok  = blockIdx.x;
  const int slot = blockIdx.y;
  const int lane = threadIdx.x;

  const float* w;
  int off;
  if (slot < NH) { off = slot * DH;                 w = qw; }
  else           { off = NH * DH + (slot - NH)*DH;  w = kw; }

  float* x = qkv + (size_t)tok * QKV_N + off;
  float x1 = x[lane];
  float x2 = x[lane + 64];

  float ss = x1*x1 + x2*x2;
  #pragma unroll
  for (int o = 32; o > 0; o >>= 1) ss += __shfl_xor(ss, o, 64);
  const float rs = 1.0f / sqrtf(ss * (1.0f / 128.0f) + 1e-6f);

  const float n1 = x1 * rs * w[lane];
  const float n2 = x2 * rs * w[lane + 64];

  const float pos = (float)positions[tok];
  const float inv_freq = powf(10000.0f, -(float)lane * (1.0f / 64.0f));
  const float ang = pos * inv_freq;
  float sn, cs;
  sincosf(ang, &sn, &cs);

  x[lane]      = n1 * cs - n2 * sn;
  x[lane + 64] = n2 * cs + n1 * sn;
}

// ---------------------------------------------------------------------------
// fp32 causal flash attention, GQA (kv head = h >> 2). One block per
// (q-tile of 32, head, batch). 256 threads. Online softmax.
// ---------------------------------------------------------------------------
__global__ __launch_bounds__(256)
void attn_flash(const float* __restrict__ qkv, float* __restrict__ att) {
  __shared__ float Qs[32][132];
  __shared__ float Ks[32][132];
  __shared__ float Vs[32][132];
  __shared__ float Ss[32][33];
  __shared__ float mrow[32], lrow[32], arow[32];

  const int qt  = blockIdx.x;   // 0..63
  const int h   = blockIdx.y;   // 0..15
  const int b   = blockIdx.z;   // 0..1
  const int kvh = h >> 2;       // GQA: 4 q heads per kv head
  const int t   = threadIdx.x;

  const float* qbase = qkv + (size_t)b * S_LEN * QKV_N;

  // Load Q tile (32 x 128)
  #pragma unroll
  for (int i = 0; i < 4; ++i) {
    const int f = t + i * 256;
    const int r = f >> 5, d4 = (f & 31) * 4;
    *(float4*)&Qs[r][d4] =
        *(const float4*)(qbase + (size_t)(qt*32 + r) * QKV_N + h * DH + d4);
  }
  if (t < 32) { mrow[t] = -INFINITY; lrow[t] = 0.f; }

  float o[16];
  #pragma unroll
  for (int i = 0; i < 16; ++i) o[i] = 0.f;

  const int r  = t >> 3;          // query row (0..31), 8 threads per row
  const int cb = (t & 7) * 4;     // score col base
  const int db = (t & 7) * 16;    // output d base
  const int tq = qt * 32 + r;
  const float scale = 0.08838834764831845f;  // 128^-0.5

  for (int kt = 0; kt <= qt; ++kt) {
    // Load K,V tiles (guarded against prev iter by the loop-end sync)
    #pragma unroll
    for (int i = 0; i < 4; ++i) {
      const int f = t + i * 256;
      const int rr = f >> 5, d4 = (f & 31) * 4;
      const float* krow = qbase + (size_t)(kt*32 + rr) * QKV_N + kvh * DH;
      *(float4*)&Ks[rr][d4] = *(const float4*)(krow + NH * DH + d4);
      *(float4*)&Vs[rr][d4] = *(const float4*)(krow + NH * DH + NKV * DH + d4);
    }
    __syncthreads();

    // Scores: each thread does 4 cols x 128-deep dots
    float s0 = 0.f, s1 = 0.f, s2 = 0.f, s3 = 0.f;
    #pragma unroll 8
    for (int k4 = 0; k4 < 32; ++k4) {
      const float4 q  = *(const float4*)&Qs[r][k4 * 4];
      const float4 ka = *(const float4*)&Ks[cb + 0][k4 * 4];
      const float4 kb = *(const float4*)&Ks[cb + 1][k4 * 4];
      const float4 kc = *(const float4*)&Ks[cb + 2][k4 * 4];
      const float4 kd = *(const float4*)&Ks[cb + 3][k4 * 4];
      s0 += q.x*ka.x + q.y*ka.y + q.z*ka.z + q.w*ka.w;
      s1 += q.x*kb.x + q.y*kb.y + q.z*kb.z + q.w*kb.w;
      s2 += q.x*kc.x + q.y*kc.y + q.z*kc.z + q.w*kc.w;
      s3 += q.x*kd.x + q.y*kd.y + q.z*kd.z + q.w*kd.w;
    }
    const int tk = kt * 32 + cb;
    Ss[r][cb + 0] = (tk + 0 <= tq) ? s0 * scale : -INFINITY;
    Ss[r][cb + 1] = (tk + 1 <= tq) ? s1 * scale : -INFINITY;
    Ss[r][cb + 2] = (tk + 2 <= tq) ? s2 * scale : -INFINITY;
    Ss[r][cb + 3] = (tk + 3 <= tq) ? s3 * scale : -INFINITY;
    __syncthreads();

    // Online softmax per row (32 threads; serial baseline)
    if (t < 32) {
      const float mprev = mrow[t];
      float mnew = mprev;
      #pragma unroll
      for (int c = 0; c < 32; ++c) mnew = fmaxf(mnew, Ss[t][c]);
      const float alpha = expf(mprev - mnew);
      float lnew = lrow[t] * alpha;
      #pragma unroll
      for (int c = 0; c < 32; ++c) {
        const float p = expf(Ss[t][c] - mnew);
        Ss[t][c] = p;
        lnew += p;
      }
      mrow[t] = mnew; lrow[t] = lnew; arow[t] = alpha;
    }
    __syncthreads();

    // O update: each thread owns row r, 16 d's
    const float alpha = arow[r];
    #pragma unroll
    for (int i = 0; i < 16; ++i) o[i] *= alpha;
    #pragma unroll 4
    for (int c = 0; c < 32; ++c) {
      const float p = Ss[r][c];
      const float4 v0 = *(const float4*)&Vs[c][db + 0];
      const float4 v1 = *(const float4*)&Vs[c][db + 4];
      const float4 v2 = *(const float4*)&Vs[c][db + 8];
      const float4 v3 = *(const float4*)&Vs[c][db + 12];
      o[0]  += p * v0.x; o[1]  += p * v0.y; o[2]  += p * v0.z; o[3]  += p * v0.w;
      o[4]  += p * v1.x; o[5]  += p * v1.y; o[6]  += p * v1.z; o[7]  += p * v1.w;
      o[8]  += p * v2.x; o[9]  += p * v2.y; o[10] += p * v2.z; o[11] += p * v2.w;
      o[12] += p * v3.x; o[13] += p * v3.y; o[14] += p * v3.z; o[15] += p * v3.w;
    }
    __syncthreads();
  }

  const float linv = 1.0f / lrow[r];
  float* orow = att + (size_t)(b * S_LEN + qt*32 + r) * (NH * DH) + h * DH + db;
  *(float4*)&orow[0]  = make_float4(o[0]*linv,  o[1]*linv,  o[2]*linv,  o[3]*linv);
  *(float4*)&orow[4]  = make_float4(o[4]*linv,  o[5]*linv,  o[6]*linv,  o[7]*linv);
  *(float4*)&orow[8]  = make_float4(o[8]*linv,  o[9]*linv,  o[10]*linv, o[11]*linv);
  *(float4*)&orow[12] = make_float4(o[12]*linv, o[13]*linv, o[14]*linv, o[15]*linv);
}

// ---------------------------------------------------------------------------
extern "C" void kernel_launch(void* const* d_in, const int* in_sizes, int n_in,
                              void* d_out, int out_size, void* d_ws, size_t ws_size,
                              hipStream_t stream) {
  const int*   positions = (const int*)  d_in[0];
  const float* hidden    = (const float*)d_in[1];
  const float* w_qkv     = (const float*)d_in[2];
  const float* w_o       = (const float*)d_in[3];
  const float* q_norm_w  = (const float*)d_in[4];
  const float* k_norm_w  = (const float*)d_in[5];
  float* out = (float*)d_out;

  float* qkv = (float*)d_ws;                       // TOKS x 3072
  float* att = qkv + (size_t)TOKS * QKV_N;         // TOKS x 2048

  // 1. QKV projection: (4096 x 2048) @ (2048 x 3072)
  gemm_f32<<<dim3(QKV_N / 64, TOKS / 64), 256, 0, stream>>>(
      hidden, w_qkv, qkv, TOKS, QKV_N, HS);

  // 2. RMSNorm + RoPE on q (16 heads) and k (4 heads), in place
  norm_rope<<<dim3(TOKS, NH + NKV), 64, 0, stream>>>(
      qkv, positions, q_norm_w, k_norm_w);

  // 3. Causal GQA flash attention
  attn_flash<<<dim3(S_LEN / 32, NH, 2), 256, 0, stream>>>(qkv, att);

  // 4. Output projection: (4096 x 2048) @ (2048 x 2048)
  gemm_f32<<<dim3(HS / 64, TOKS / 64), 256, 0, stream>>>(
      att, w_o, out, TOKS, HS, HS);
}

// Round 2
// 626.803 us; speedup vs baseline: 5.6606x; 5.6606x over previous
//
#include <hip/hip_runtime.h>
#include <math.h>

#define TOKS 4096
#define HS   2048
#define QKV_N 3072
#define S_LEN 2048
#define NH   16
#define NKV  4
#define DH   128

typedef __attribute__((ext_vector_type(8))) short short8;
typedef __attribute__((ext_vector_type(4))) float f32x4;

static __device__ __forceinline__ unsigned short f2bf(float f) {
  unsigned u = __builtin_bit_cast(unsigned, f);
  u += 0x7fffu + ((u >> 16) & 1u);           // round-to-nearest-even
  return (unsigned short)(u >> 16);
}

// ---------------------------------------------------------------------------
// f32 -> bf16 elementwise, 8 elems/thread
// ---------------------------------------------------------------------------
__global__ __launch_bounds__(256)
void cvt_bf16(const float* __restrict__ in, unsigned short* __restrict__ out) {
  const size_t i = ((size_t)blockIdx.x * 256 + threadIdx.x) * 8;
  float4 a = *(const float4*)(in + i);
  float4 b = *(const float4*)(in + i + 4);
  short8 r;
  r[0] = f2bf(a.x); r[1] = f2bf(a.y); r[2] = f2bf(a.z); r[3] = f2bf(a.w);
  r[4] = f2bf(b.x); r[5] = f2bf(b.y); r[6] = f2bf(b.z); r[7] = f2bf(b.w);
  *(short8*)(out + i) = r;
}

// ---------------------------------------------------------------------------
// Transpose + cvt: out[c][r] = bf16(in[r][c]).  in rows have stride ldin.
// z-mapping: in += (z/z_mod)*in_z_hi + (z%z_mod)*in_z_lo; out += z*out_z.
// ---------------------------------------------------------------------------
__global__ __launch_bounds__(256)
void transpose_cvt(const float* __restrict__ in, unsigned short* __restrict__ out,
                   int R, int C, int ldin,
                   long in_z_hi, long in_z_lo, int z_mod, long out_z) {
  __shared__ float tile[32][33];
  const int z = blockIdx.z;
  in  += (size_t)(z / z_mod) * in_z_hi + (size_t)(z % z_mod) * in_z_lo;
  out += (size_t)z * out_z;
  const int r0 = blockIdx.x * 32, c0 = blockIdx.y * 32;
  const int tx = threadIdx.x & 31, ty = threadIdx.x >> 5;  // 32 x 8
  #pragma unroll
  for (int i = 0; i < 4; ++i)
    tile[ty + i * 8][tx] = in[(size_t)(r0 + ty + i * 8) * ldin + c0 + tx];
  __syncthreads();
  #pragma unroll
  for (int i = 0; i < 4; ++i)
    out[(size_t)(c0 + ty + i * 8) * R + r0 + tx] = f2bf(tile[tx][ty + i * 8]);
}

// ---------------------------------------------------------------------------
// RMSNorm + RoPE on q/k heads of the f32 qkv buffer, output bf16 into
// Qb [B][NH][S][DH] (q pre-scaled by 1/sqrt(DH)) and Kb [B][NKV][S][DH].
// ---------------------------------------------------------------------------
__global__ __launch_bounds__(64)
void norm_rope_cvt(const float* __restrict__ qkv, const int* __restrict__ positions,
                   const float* __restrict__ qw, const float* __restrict__ kw,
                   unsigned short* __restrict__ Qb, unsigned short* __restrict__ Kb) {
  const int tok  = blockIdx.x;
  const int slot = blockIdx.y;   // 0..15 q heads, 16..19 k heads
  const int lane = threadIdx.x;
  const int b = tok >> 11, s = tok & 2047;

  const float* x; const float* wgt; unsigned short* outp; float scale;
  if (slot < NH) {
    x = qkv + (size_t)tok * QKV_N + slot * DH;  wgt = qw;
    outp = Qb + (((size_t)b * NH + slot) * S_LEN + s) * DH;
    scale = 0.08838834764831845f;               // 128^-0.5 folded into Q
  } else {
    const int kh = slot - NH;
    x = qkv + (size_t)tok * QKV_N + NH * DH + kh * DH;  wgt = kw;
    outp = Kb + (((size_t)b * NKV + kh) * S_LEN + s) * DH;
    scale = 1.0f;
  }

  float x1 = x[lane], x2 = x[lane + 64];
  float ss = x1 * x1 + x2 * x2;
  #pragma unroll
  for (int o = 32; o > 0; o >>= 1) ss += __shfl_xor(ss, o, 64);
  const float rs = 1.0f / sqrtf(ss * (1.0f / 128.0f) + 1e-6f);
  const float n1 = x1 * rs * wgt[lane];
  const float n2 = x2 * rs * wgt[lane + 64];

  const float pos = (float)positions[tok];
  const float inv_freq = powf(10000.0f, -(float)lane * (1.0f / 64.0f));
  float sn, cs;
  sincosf(pos * inv_freq, &sn, &cs);

  outp[lane]      = f2bf((n1 * cs - n2 * sn) * scale);
  outp[lane + 64] = f2bf((n2 * cs + n1 * sn) * scale);
}

// ---------------------------------------------------------------------------
// bf16 MFMA GEMM (m97 structure): C[M][N] f32 = A[M][K] @ Bt[N][K]^T.
// 128x128 tile, BK=32, 256 threads (4 waves 2x2), global_load_lds width 16.
// ---------------------------------------------------------------------------
__global__ __launch_bounds__(256)
void gemm_bf16(const unsigned short* __restrict__ A, const unsigned short* __restrict__ Bt,
               float* __restrict__ C, int M, int N, int K) {
  __shared__ unsigned short As[128 * 32];
  __shared__ unsigned short Bs[128 * 32];
  const int t = threadIdx.x, w = t >> 6, l = t & 63;
  const int lm = l & 15, lr = l >> 4;
  const int bn = blockIdx.x * 128, bm = blockIdx.y * 128;
  const int wr = w >> 1, wc = w & 1;

  f32x4 acc[4][4];
  #pragma unroll
  for (int i = 0; i < 4; ++i)
    #pragma unroll
    for (int j = 0; j < 4; ++j) acc[i][j] = {0.f, 0.f, 0.f, 0.f};

  const int srow = l >> 2;          // 0..15 within a 16-row chunk
  const int scol = (l & 3) * 8;     // k-elem offset

  for (int k0 = 0; k0 < K; k0 += 32) {
    #pragma unroll
    for (int c = 0; c < 2; ++c) {
      const int rowA = (w + c * 4) * 16;   // wave-uniform chunk base
      const unsigned short* ga = A + (size_t)(bm + rowA + srow) * K + k0 + scol;
      const unsigned short* gb = Bt + (size_t)(bn + rowA + srow) * K + k0 + scol;
      __builtin_amdgcn_global_load_lds(
          (const __attribute__((address_space(1))) void*)ga,
          (__attribute__((address_space(3))) void*)(As + rowA * 32), 16, 0, 0);
      __builtin_amdgcn_global_load_lds(
          (const __attribute__((address_space(1))) void*)gb,
          (__attribute__((address_space(3))) void*)(Bs + rowA * 32), 16, 0, 0);
    }
    __syncthreads();

    short8 af[4], bf[4];
    #pragma unroll
    for (int mi = 0; mi < 4; ++mi)
      af[mi] = *(const short8*)(As + (wr * 64 + mi * 16 + lm) * 32 + lr * 8);
    #pragma unroll
    for (int ni = 0; ni < 4; ++ni)
      bf[ni] = *(const short8*)(Bs + (wc * 64 + ni * 16 + lm) * 32 + lr * 8);
    #pragma unroll
    for (int mi = 0; mi < 4; ++mi)
      #pragma unroll
      for (int ni = 0; ni < 4; ++ni)
        acc[mi][ni] = __builtin_amdgcn_mfma_f32_16x16x32_bf16(af[mi], bf[ni], acc[mi][ni], 0, 0, 0);
    __syncthreads();
  }

  // C/D layout (m89): col = lane&15, row = (lane>>4)*4 + j
  #pragma unroll
  for (int mi = 0; mi < 4; ++mi)
    #pragma unroll
    for (int ni = 0; ni < 4; ++ni)
      #pragma unroll
      for (int j = 0; j < 4; ++j)
        C[(size_t)(bm + wr * 64 + mi * 16 + lr * 4 + j) * N + bn + wc * 64 + ni * 16 + lm] =
            acc[mi][ni][j];
}

// ---------------------------------------------------------------------------
// MFMA causal GQA flash attention.
// Qb [B][NH][S][DH] bf16 (pre-scaled), Kb [B][NKV][S][DH] bf16,
// Vt [B][NKV][DH][S] bf16, att out [B*S][NH*DH] bf16.
// Block = 4 waves; wave w owns q-rows [qt*64+w*16, +16); KV tile = 32.
// K/V fragments come straight from global (L1/L2-resident); no __syncthreads.
// ---------------------------------------------------------------------------
__global__ __launch_bounds__(256)
void attn_mfma(const unsigned short* __restrict__ Qb, const unsigned short* __restrict__ Kb,
               const unsigned short* __restrict__ Vt, unsigned short* __restrict__ att) {
  __shared__ unsigned short P_lds[4][16 * 32];
  const int qt = (gridDim.x - 1) - blockIdx.x;   // long blocks first
  const int h  = blockIdx.y;
  const int b  = blockIdx.z;
  const int kvh = h >> 2;
  const int t = threadIdx.x, w = t >> 6, l = t & 63;
  const int lm = l & 15, lr = l >> 4;
  const int row0 = qt * 64 + w * 16;

  // Q A-frags: lane holds A[m=lm][k = kc*32 + lr*8 + i]
  const unsigned short* qrow = Qb + (((size_t)(b * NH + h)) * S_LEN + row0 + lm) * DH + lr * 8;
  short8 qf[4];
  #pragma unroll
  for (int kc = 0; kc < 4; ++kc) qf[kc] = *(const short8*)(qrow + kc * 32);

  const unsigned short* kbase = Kb + ((size_t)(b * NKV + kvh)) * S_LEN * DH;
  const unsigned short* vbase = Vt + (((size_t)(b * NKV + kvh)) * DH + lm) * S_LEN + lr * 8;

  f32x4 o[8];
  #pragma unroll
  for (int i = 0; i < 8; ++i) o[i] = {0.f, 0.f, 0.f, 0.f};
  float m_run[4], l_run[4];
  #pragma unroll
  for (int j = 0; j < 4; ++j) { m_run[j] = -1e30f; l_run[j] = 0.f; }

  const int nkt = (row0 + 15) / 32 + 1;
  for (int kt = 0; kt < nkt; ++kt) {
    const int kb0 = kt * 32;

    // ---- S = Q K^T (two 16-col groups) ----
    f32x4 s[2];
    s[0] = {0.f, 0.f, 0.f, 0.f}; s[1] = {0.f, 0.f, 0.f, 0.f};
    #pragma unroll
    for (int n2 = 0; n2 < 2; ++n2) {
      const unsigned short* kr = kbase + (size_t)(kb0 + n2 * 16 + lm) * DH + lr * 8;
      #pragma unroll
      for (int kc = 0; kc < 4; ++kc) {
        short8 kf = *(const short8*)(kr + kc * 32);
        s[n2] = __builtin_amdgcn_mfma_f32_16x16x32_bf16(qf[kc], kf, s[n2], 0, 0, 0);
      }
    }

    // ---- causal mask (only the last tile of each wave is partial) ----
    if (kt == nkt - 1) {
      #pragma unroll
      for (int n2 = 0; n2 < 2; ++n2) {
        const int ck = kb0 + n2 * 16 + lm;
        #pragma unroll
        for (int j = 0; j < 4; ++j)
          if (ck > row0 + lr * 4 + j) s[n2][j] = -1e30f;
      }
    }

    // ---- online softmax (wave-parallel: reduce across the 16 col-lanes) ----
    float mt[4], ps0[4], ps1[4], sum[4], alpha[4];
    #pragma unroll
    for (int j = 0; j < 4; ++j) mt[j] = fmaxf(s[0][j], s[1][j]);
    #pragma unroll
    for (int msk = 1; msk < 16; msk <<= 1)
      #pragma unroll
      for (int j = 0; j < 4; ++j) mt[j] = fmaxf(mt[j], __shfl_xor(mt[j], msk, 64));
    #pragma unroll
    for (int j = 0; j < 4; ++j) {
      const float mn = fmaxf(m_run[j], mt[j]);
      alpha[j] = __expf(m_run[j] - mn);
      m_run[j] = mn;
      ps0[j] = __expf(s[0][j] - mn);
      ps1[j] = __expf(s[1][j] - mn);
      sum[j] = ps0[j] + ps1[j];
    }
    #pragma unroll
    for (int msk = 1; msk < 16; msk <<= 1)
      #pragma unroll
      for (int j = 0; j < 4; ++j) sum[j] += __shfl_xor(sum[j], msk, 64);
    #pragma unroll
    for (int j = 0; j < 4; ++j) l_run[j] = l_run[j] * alpha[j] + sum[j];
    #pragma unroll
    for (int ng = 0; ng < 8; ++ng)
      #pragma unroll
      for (int j = 0; j < 4; ++j) o[ng][j] *= alpha[j];

    // ---- transpose P through wave-private LDS: [m=lr*4+j][kv=n2*16+lm] ----
    unsigned short* P = &P_lds[w][0];
    #pragma unroll
    for (int n2 = 0; n2 < 2; ++n2)
      #pragma unroll
      for (int j = 0; j < 4; ++j)
        P[(lr * 4 + j) * 32 + n2 * 16 + lm] = f2bf(n2 ? ps1[j] : ps0[j]);
    __asm__ volatile("s_waitcnt lgkmcnt(0)" ::: "memory");
    short8 pf = *(const short8*)(P + lm * 32 + lr * 8);   // A[m=lm][kv=lr*8+i]

    // ---- O += P V ----
    const unsigned short* vr = vbase + kb0;
    #pragma unroll
    for (int ng = 0; ng < 8; ++ng) {
      short8 vf = *(const short8*)(vr + (size_t)ng * 16 * S_LEN);
      o[ng] = __builtin_amdgcn_mfma_f32_16x16x32_bf16(pf, vf, o[ng], 0, 0, 0);
    }
  }

  // ---- epilogue: normalize, store bf16 ----
  #pragma unroll
  for (int j = 0; j < 4; ++j) {
    const float linv = 1.0f / l_run[j];
    unsigned short* ar = att + ((size_t)(b * S_LEN) + row0 + lr * 4 + j) * (NH * DH) + h * DH + lm;
    #pragma unroll
    for (int ng = 0; ng < 8; ++ng) ar[ng * 16] = f2bf(o[ng][j] * linv);
  }
}

// ---------------------------------------------------------------------------
extern "C" void kernel_launch(void* const* d_in, const int* in_sizes, int n_in,
                              void* d_out, int out_size, void* d_ws, size_t ws_size,
                              hipStream_t stream) {
  const int*   positions = (const int*)  d_in[0];
  const float* hidden    = (const float*)d_in[1];
  const float* w_qkv     = (const float*)d_in[2];
  const float* w_o       = (const float*)d_in[3];
  const float* q_norm_w  = (const float*)d_in[4];
  const float* k_norm_w  = (const float*)d_in[5];
  float* out = (float*)d_out;

  char* ws = (char*)d_ws;
  // [0, 50.33MB): qkv f32; first 16.78MB later reused for att bf16
  float*          qkv   = (float*)ws;
  unsigned short* att   = (unsigned short*)ws;
  char* region = ws + (size_t)TOKS * QKV_N * 4;                 // +50,331,648
  unsigned short* hb    = (unsigned short*)region;              // 16.78MB (dies after qkv GEMM)
  unsigned short* Qb    = (unsigned short*)region;              // reuses hb
  unsigned short* wqkvt = (unsigned short*)(region + 16777216); // 12.58MB (dies after qkv GEMM)
  unsigned short* Kb    = (unsigned short*)(region + 16777216); // 4.19MB
  unsigned short* Vt    = (unsigned short*)(region + 20971520); // 4.19MB
  unsigned short* wot   = (unsigned short*)(region + 25165824); // 8.39MB
  // total = 50,331,648 + 33,554,432 = 83,886,080 bytes (same as round-0 footprint)

  // 1. hidden f32 -> bf16
  cvt_bf16<<<(TOKS * HS) / (256 * 8), 256, 0, stream>>>(hidden, hb);
  // 2. w_qkv [2048][3072] -> wqkvt bf16 [3072][2048]
  transpose_cvt<<<dim3(HS / 32, QKV_N / 32, 1), 256, 0, stream>>>(
      w_qkv, wqkvt, HS, QKV_N, QKV_N, 0, 0, 1, 0);
  // 3. qkv = hidden @ w_qkv   (f32 out)
  gemm_bf16<<<dim3(QKV_N / 128, TOKS / 128), 256, 0, stream>>>(
      hb, wqkvt, qkv, TOKS, QKV_N, HS);
  // 4. RMSNorm + RoPE -> Qb, Kb (bf16)
  norm_rope_cvt<<<dim3(TOKS, NH + NKV), 64, 0, stream>>>(
      qkv, positions, q_norm_w, k_norm_w, Qb, Kb);
  // 5. V slice of qkv -> Vt bf16 [B][NKV][DH][S]
  transpose_cvt<<<dim3(S_LEN / 32, DH / 32, 2 * NKV), 256, 0, stream>>>(
      qkv + (NH + NKV) * DH, Vt, S_LEN, DH, QKV_N,
      (long)S_LEN * QKV_N, DH, NKV, (long)DH * S_LEN);
  // 6. w_o [2048][2048] -> wot bf16 [2048][2048] (transposed)
  transpose_cvt<<<dim3(HS / 32, HS / 32, 1), 256, 0, stream>>>(
      w_o, wot, HS, HS, HS, 0, 0, 1, 0);
  // 7. attention -> att bf16 (overwrites dead qkv head region)
  attn_mfma<<<dim3(S_LEN / 64, NH, 2), 256, 0, stream>>>(Qb, Kb, Vt, att);
  // 8. out = att @ w_o (f32 out)
  gemm_bf16<<<dim3(HS / 128, TOKS / 128), 256, 0, stream>>>(
      att, wot, out, TOKS, HS, HS);
}

// Round 3
// 397.221 us; speedup vs baseline: 8.9322x; 1.5780x over previous
//
#include <hip/hip_runtime.h>
#include <math.h>

#define TOKS 4096
#define HS   2048
#define QKV_N 3072
#define S_LEN 2048
#define NH   16
#define NKV  4
#define DH   128

typedef __attribute__((ext_vector_type(8))) short short8;
typedef __attribute__((ext_vector_type(4))) float f32x4;

static __device__ __forceinline__ unsigned short f2bf(float f) {
  unsigned u = __builtin_bit_cast(unsigned, f);
  u += 0x7fffu + ((u >> 16) & 1u);           // round-to-nearest-even
  return (unsigned short)(u >> 16);
}

// ---------------------------------------------------------------------------
// f32 -> bf16 elementwise, 8 elems/thread
// ---------------------------------------------------------------------------
__global__ __launch_bounds__(256)
void cvt_bf16(const float* __restrict__ in, unsigned short* __restrict__ out) {
  const size_t i = ((size_t)blockIdx.x * 256 + threadIdx.x) * 8;
  float4 a = *(const float4*)(in + i);
  float4 b = *(const float4*)(in + i + 4);
  short8 r;
  r[0] = f2bf(a.x); r[1] = f2bf(a.y); r[2] = f2bf(a.z); r[3] = f2bf(a.w);
  r[4] = f2bf(b.x); r[5] = f2bf(b.y); r[6] = f2bf(b.z); r[7] = f2bf(b.w);
  *(short8*)(out + i) = r;
}

// ---------------------------------------------------------------------------
// Transpose + cvt: out[c][r] = bf16(in[r][c]).  in rows have stride ldin.
// ---------------------------------------------------------------------------
__global__ __launch_bounds__(256)
void transpose_cvt(const float* __restrict__ in, unsigned short* __restrict__ out,
                   int R, int C, int ldin,
                   long in_z_hi, long in_z_lo, int z_mod, long out_z) {
  __shared__ float tile[32][33];
  const int z = blockIdx.z;
  in  += (size_t)(z / z_mod) * in_z_hi + (size_t)(z % z_mod) * in_z_lo;
  out += (size_t)z * out_z;
  const int r0 = blockIdx.x * 32, c0 = blockIdx.y * 32;
  const int tx = threadIdx.x & 31, ty = threadIdx.x >> 5;  // 32 x 8
  #pragma unroll
  for (int i = 0; i < 4; ++i)
    tile[ty + i * 8][tx] = in[(size_t)(r0 + ty + i * 8) * ldin + c0 + tx];
  __syncthreads();
  #pragma unroll
  for (int i = 0; i < 4; ++i)
    out[(size_t)(c0 + ty + i * 8) * R + r0 + tx] = f2bf(tile[tx][ty + i * 8]);
}

// ---------------------------------------------------------------------------
// RMSNorm + RoPE -> bf16 Qb [B][NH][S][DH] (pre-scaled by 1/sqrt(DH)),
// Kb [B][NKV][S][DH].
// ---------------------------------------------------------------------------
__global__ __launch_bounds__(64)
void norm_rope_cvt(const float* __restrict__ qkv, const int* __restrict__ positions,
                   const float* __restrict__ qw, const float* __restrict__ kw,
                   unsigned short* __restrict__ Qb, unsigned short* __restrict__ Kb) {
  const int tok  = blockIdx.x;
  const int slot = blockIdx.y;
  const int lane = threadIdx.x;
  const int b = tok >> 11, s = tok & 2047;

  const float* x; const float* wgt; unsigned short* outp; float scale;
  if (slot < NH) {
    x = qkv + (size_t)tok * QKV_N + slot * DH;  wgt = qw;
    outp = Qb + (((size_t)b * NH + slot) * S_LEN + s) * DH;
    scale = 0.08838834764831845f;
  } else {
    const int kh = slot - NH;
    x = qkv + (size_t)tok * QKV_N + NH * DH + kh * DH;  wgt = kw;
    outp = Kb + (((size_t)b * NKV + kh) * S_LEN + s) * DH;
    scale = 1.0f;
  }

  float x1 = x[lane], x2 = x[lane + 64];
  float ss = x1 * x1 + x2 * x2;
  #pragma unroll
  for (int o = 32; o > 0; o >>= 1) ss += __shfl_xor(ss, o, 64);
  const float rs = 1.0f / sqrtf(ss * (1.0f / 128.0f) + 1e-6f);
  const float n1 = x1 * rs * wgt[lane];
  const float n2 = x2 * rs * wgt[lane + 64];

  const float pos = (float)positions[tok];
  // 10000^(-lane/64) = exp2(-lane * log2(10000)/64)
  const float inv_freq = exp2f(-(float)lane * (13.287712379549449f / 64.0f));
  float sn, cs;
  sincosf(pos * inv_freq, &sn, &cs);

  outp[lane]      = f2bf((n1 * cs - n2 * sn) * scale);
  outp[lane + 64] = f2bf((n2 * cs + n1 * sn) * scale);
}

// ---------------------------------------------------------------------------
// bf16 MFMA GEMM (m97 structure): C[M][N] f32 = A[M][K] @ Bt[N][K]^T.
// ---------------------------------------------------------------------------
__global__ __launch_bounds__(256)
void gemm_bf16(const unsigned short* __restrict__ A, const unsigned short* __restrict__ Bt,
               float* __restrict__ C, int M, int N, int K) {
  __shared__ unsigned short As[128 * 32];
  __shared__ unsigned short Bs[128 * 32];
  const int t = threadIdx.x, w = t >> 6, l = t & 63;
  const int lm = l & 15, lr = l >> 4;
  const int bn = blockIdx.x * 128, bm = blockIdx.y * 128;
  const int wr = w >> 1, wc = w & 1;

  f32x4 acc[4][4];
  #pragma unroll
  for (int i = 0; i < 4; ++i)
    #pragma unroll
    for (int j = 0; j < 4; ++j) acc[i][j] = {0.f, 0.f, 0.f, 0.f};

  const int srow = l >> 2;
  const int scol = (l & 3) * 8;

  for (int k0 = 0; k0 < K; k0 += 32) {
    #pragma unroll
    for (int c = 0; c < 2; ++c) {
      const int rowA = (w + c * 4) * 16;
      const unsigned short* ga = A + (size_t)(bm + rowA + srow) * K + k0 + scol;
      const unsigned short* gb = Bt + (size_t)(bn + rowA + srow) * K + k0 + scol;
      __builtin_amdgcn_global_load_lds(
          (const __attribute__((address_space(1))) void*)ga,
          (__attribute__((address_space(3))) void*)(As + rowA * 32), 16, 0, 0);
      __builtin_amdgcn_global_load_lds(
          (const __attribute__((address_space(1))) void*)gb,
          (__attribute__((address_space(3))) void*)(Bs + rowA * 32), 16, 0, 0);
    }
    __syncthreads();

    short8 af[4], bf[4];
    #pragma unroll
    for (int mi = 0; mi < 4; ++mi)
      af[mi] = *(const short8*)(As + (wr * 64 + mi * 16 + lm) * 32 + lr * 8);
    #pragma unroll
    for (int ni = 0; ni < 4; ++ni)
      bf[ni] = *(const short8*)(Bs + (wc * 64 + ni * 16 + lm) * 32 + lr * 8);
    #pragma unroll
    for (int mi = 0; mi < 4; ++mi)
      #pragma unroll
      for (int ni = 0; ni < 4; ++ni)
        acc[mi][ni] = __builtin_amdgcn_mfma_f32_16x16x32_bf16(af[mi], bf[ni], acc[mi][ni], 0, 0, 0);
    __syncthreads();
  }

  #pragma unroll
  for (int mi = 0; mi < 4; ++mi)
    #pragma unroll
    for (int ni = 0; ni < 4; ++ni)
      #pragma unroll
      for (int j = 0; j < 4; ++j)
        C[(size_t)(bm + wr * 64 + mi * 16 + lr * 4 + j) * N + bn + wc * 64 + ni * 16 + lm] =
            acc[mi][ni][j];
}

// ---------------------------------------------------------------------------
// MFMA causal GQA flash attention v3.
// 4 waves/block, wave owns 32 q-rows (2 m-groups), KVBLK=64.
// K[64x128] + Vt[128x64] staged in LDS (double-buffered, global_load_lds,
// pre-swizzled source), XOR bank swizzle everywhere, setprio on MFMA clusters.
// ---------------------------------------------------------------------------
__global__ __launch_bounds__(256)
void attn_mfma(const unsigned short* __restrict__ Qb, const unsigned short* __restrict__ Kb,
               const unsigned short* __restrict__ Vt, unsigned short* __restrict__ att) {
  __shared__ unsigned short Ks_[2][64 * 128];   // 32 KB
  __shared__ unsigned short Vs_[2][128 * 64];   // 32 KB
  __shared__ unsigned short Pl[4][32 * 64];     // 16 KB

  const int x  = blockIdx.x;
  const int qb = (x < 8) ? (15 - x) : (x - 8);   // LPT-ish pairing of long/short
  const int h  = blockIdx.y;
  const int b  = blockIdx.z;
  const int kvh = h >> 2;
  const int t = threadIdx.x, w = t >> 6, l = t & 63;
  const int lm = l & 15, lr = l >> 4;
  const int row0 = qb * 128 + w * 32;            // wave's first q row

  const unsigned short* qbase = Qb + ((size_t)(b * NH + h)) * S_LEN * DH;
  const unsigned short* kbase = Kb + ((size_t)(b * NKV + kvh)) * S_LEN * DH;
  const unsigned short* vtbase = Vt + ((size_t)(b * NKV + kvh)) * DH * S_LEN;

  // Q A-frags: lane holds A[m=lm][k = kc*32 + lr*8 + i]
  short8 qf[2][4];
  #pragma unroll
  for (int m = 0; m < 2; ++m)
    #pragma unroll
    for (int kc = 0; kc < 4; ++kc)
      qf[m][kc] = *(const short8*)(qbase + (size_t)(row0 + m * 16 + lm) * DH + kc * 32 + lr * 8);

  f32x4 o[2][8];
  #pragma unroll
  for (int m = 0; m < 2; ++m)
    #pragma unroll
    for (int ng = 0; ng < 8; ++ng) o[m][ng] = {0.f, 0.f, 0.f, 0.f};
  float m_run[2][4], l_run[2][4];
  #pragma unroll
  for (int m = 0; m < 2; ++m)
    #pragma unroll
    for (int j = 0; j < 4; ++j) { m_run[m][j] = -1e30f; l_run[m][j] = 0.f; }

  // Stage tile kb0 into buffer bufi. Linear LDS dest (global_load_lds),
  // source pre-swizzled: slot ^= (row & 7) within each row.
  auto stage = [&](int bufi, int kb0) {
    #pragma unroll
    for (int i = 0; i < 4; ++i) {
      const int rk = w * 16 + i * 4 + (l >> 4);      // K tile row 0..63
      const unsigned short* gk =
          kbase + (size_t)(kb0 + rk) * DH + (((l & 15) ^ (rk & 7)) * 8);
      __builtin_amdgcn_global_load_lds(
          (const __attribute__((address_space(1))) void*)gk,
          (__attribute__((address_space(3))) void*)(&Ks_[bufi][(w * 16 + i * 4) * 128]),
          16, 0, 0);
      const int rv = w * 32 + i * 8 + (l >> 3);      // V tile row (d) 0..127
      const unsigned short* gv =
          vtbase + (size_t)rv * S_LEN + kb0 + (((l & 7) ^ (rv & 7)) * 8);
      __builtin_amdgcn_global_load_lds(
          (const __attribute__((address_space(1))) void*)gv,
          (__attribute__((address_space(3))) void*)(&Vs_[bufi][(w * 32 + i * 8) * 64]),
          16, 0, 0);
    }
  };

  const int nkt = qb * 2 + 2;
  stage(0, 0);
  __syncthreads();

  for (int kt = 0; kt < nkt; ++kt) {
    const int kb0 = kt * 64;
    if (kt + 1 < nkt) stage((kt + 1) & 1, kb0 + 64);

    if (kb0 <= row0 + 31) {                       // skip fully-masked tiles
      const unsigned short* Kc = Ks_[kt & 1];
      const unsigned short* Vc = Vs_[kt & 1];
      const int rsw = (lm & 7) << 3;              // read-side swizzle

      // ---- S = Q K^T ----
      f32x4 s[2][4];
      #pragma unroll
      for (int m = 0; m < 2; ++m)
        #pragma unroll
        for (int n2 = 0; n2 < 4; ++n2) s[m][n2] = {0.f, 0.f, 0.f, 0.f};
      __builtin_amdgcn_s_setprio(1);
      #pragma unroll
      for (int n2 = 0; n2 < 4; ++n2) {
        short8 kf[4];
        #pragma unroll
        for (int kc = 0; kc < 4; ++kc)
          kf[kc] = *(const short8*)(Kc + (n2 * 16 + lm) * 128 + ((kc * 32 + lr * 8) ^ rsw));
        #pragma unroll
        for (int m = 0; m < 2; ++m)
          #pragma unroll
          for (int kc = 0; kc < 4; ++kc)
            s[m][n2] = __builtin_amdgcn_mfma_f32_16x16x32_bf16(qf[m][kc], kf[kc], s[m][n2], 0, 0, 0);
      }
      __builtin_amdgcn_s_setprio(0);

      // ---- causal mask ----
      if (kb0 + 63 > row0) {
        #pragma unroll
        for (int m = 0; m < 2; ++m) {
          const int qi = row0 + m * 16 + lr * 4;
          #pragma unroll
          for (int n2 = 0; n2 < 4; ++n2) {
            const int kvi = kb0 + n2 * 16 + lm;
            #pragma unroll
            for (int j = 0; j < 4; ++j)
              if (kvi > qi + j) s[m][n2][j] = -1e30f;
          }
        }
      }

      // ---- online softmax + P store (swizzled) ----
      #pragma unroll
      for (int m = 0; m < 2; ++m) {
        #pragma unroll
        for (int j = 0; j < 4; ++j) {
          float mt = fmaxf(fmaxf(s[m][0][j], s[m][1][j]), fmaxf(s[m][2][j], s[m][3][j]));
          mt = fmaxf(mt, __shfl_xor(mt, 1, 64));
          mt = fmaxf(mt, __shfl_xor(mt, 2, 64));
          mt = fmaxf(mt, __shfl_xor(mt, 4, 64));
          mt = fmaxf(mt, __shfl_xor(mt, 8, 64));
          const float mn = fmaxf(m_run[m][j], mt);
          const float al = __expf(m_run[m][j] - mn);
          m_run[m][j] = mn;
          const float p0 = __expf(s[m][0][j] - mn);
          const float p1 = __expf(s[m][1][j] - mn);
          const float p2 = __expf(s[m][2][j] - mn);
          const float p3 = __expf(s[m][3][j] - mn);
          float sm = (p0 + p1) + (p2 + p3);
          sm += __shfl_xor(sm, 1, 64);
          sm += __shfl_xor(sm, 2, 64);
          sm += __shfl_xor(sm, 4, 64);
          sm += __shfl_xor(sm, 8, 64);
          l_run[m][j] = l_run[m][j] * al + sm;
          #pragma unroll
          for (int ng = 0; ng < 8; ++ng) o[m][ng][j] *= al;
          const int prow = m * 16 + lr * 4 + j;
          unsigned short* Pw = &Pl[w][prow * 64];
          const int sw = (prow & 7) << 3;
          Pw[lm ^ sw]        = f2bf(p0);
          Pw[(16 + lm) ^ sw] = f2bf(p1);
          Pw[(32 + lm) ^ sw] = f2bf(p2);
          Pw[(48 + lm) ^ sw] = f2bf(p3);
        }
      }
      __asm__ volatile("s_waitcnt lgkmcnt(0)" ::: "memory");

      // ---- O += P V ----
      short8 pf[2][2];
      #pragma unroll
      for (int m = 0; m < 2; ++m)
        #pragma unroll
        for (int k2 = 0; k2 < 2; ++k2)
          pf[m][k2] = *(const short8*)(&Pl[w][(m * 16 + lm) * 64 + ((k2 * 32 + lr * 8) ^ rsw)]);
      __builtin_amdgcn_s_setprio(1);
      #pragma unroll
      for (int ng = 0; ng < 8; ++ng) {
        const short8 vf0 = *(const short8*)(Vc + (ng * 16 + lm) * 64 + ((lr * 8) ^ rsw));
        const short8 vf1 = *(const short8*)(Vc + (ng * 16 + lm) * 64 + ((32 + lr * 8) ^ rsw));
        o[0][ng] = __builtin_amdgcn_mfma_f32_16x16x32_bf16(pf[0][0], vf0, o[0][ng], 0, 0, 0);
        o[1][ng] = __builtin_amdgcn_mfma_f32_16x16x32_bf16(pf[1][0], vf0, o[1][ng], 0, 0, 0);
        o[0][ng] = __builtin_amdgcn_mfma_f32_16x16x32_bf16(pf[0][1], vf1, o[0][ng], 0, 0, 0);
        o[1][ng] = __builtin_amdgcn_mfma_f32_16x16x32_bf16(pf[1][1], vf1, o[1][ng], 0, 0, 0);
      }
      __builtin_amdgcn_s_setprio(0);
    }
    __syncthreads();
  }

  // ---- epilogue ----
  #pragma unroll
  for (int m = 0; m < 2; ++m)
    #pragma unroll
    for (int j = 0; j < 4; ++j) {
      const float linv = 1.0f / l_run[m][j];
      unsigned short* ar =
          att + ((size_t)(b * S_LEN) + row0 + m * 16 + lr * 4 + j) * (NH * DH) + h * DH + lm;
      #pragma unroll
      for (int ng = 0; ng < 8; ++ng) ar[ng * 16] = f2bf(o[m][ng][j] * linv);
    }
}

// ---------------------------------------------------------------------------
extern "C" void kernel_launch(void* const* d_in, const int* in_sizes, int n_in,
                              void* d_out, int out_size, void* d_ws, size_t ws_size,
                              hipStream_t stream) {
  const int*   positions = (const int*)  d_in[0];
  const float* hidden    = (const float*)d_in[1];
  const float* w_qkv     = (const float*)d_in[2];
  const float* w_o       = (const float*)d_in[3];
  const float* q_norm_w  = (const float*)d_in[4];
  const float* k_norm_w  = (const float*)d_in[5];
  float* out = (float*)d_out;

  char* ws = (char*)d_ws;
  float*          qkv   = (float*)ws;
  unsigned short* att   = (unsigned short*)ws;                  // reuses dead qkv
  char* region = ws + (size_t)TOKS * QKV_N * 4;                 // +50,331,648
  unsigned short* hb    = (unsigned short*)region;              // dies after qkv GEMM
  unsigned short* Qb    = (unsigned short*)region;              // reuses hb
  unsigned short* wqkvt = (unsigned short*)(region + 16777216); // dies after qkv GEMM
  unsigned short* Kb    = (unsigned short*)(region + 16777216);
  unsigned short* Vt    = (unsigned short*)(region + 20971520);
  unsigned short* wot   = (unsigned short*)(region + 25165824);

  cvt_bf16<<<(TOKS * HS) / (256 * 8), 256, 0, stream>>>(hidden, hb);
  transpose_cvt<<<dim3(HS / 32, QKV_N / 32, 1), 256, 0, stream>>>(
      w_qkv, wqkvt, HS, QKV_N, QKV_N, 0, 0, 1, 0);
  gemm_bf16<<<dim3(QKV_N / 128, TOKS / 128), 256, 0, stream>>>(
      hb, wqkvt, qkv, TOKS, QKV_N, HS);
  norm_rope_cvt<<<dim3(TOKS, NH + NKV), 64, 0, stream>>>(
      qkv, positions, q_norm_w, k_norm_w, Qb, Kb);
  transpose_cvt<<<dim3(S_LEN / 32, DH / 32, 2 * NKV), 256, 0, stream>>>(
      qkv + (NH + NKV) * DH, Vt, S_LEN, DH, QKV_N,
      (long)S_LEN * QKV_N, DH, NKV, (long)DH * S_LEN);
  transpose_cvt<<<dim3(HS / 32, HS / 32, 1), 256, 0, stream>>>(
      w_o, wot, HS, HS, HS, 0, 0, 1, 0);
  attn_mfma<<<dim3(16, NH, 2), 256, 0, stream>>>(Qb, Kb, Vt, att);
  gemm_bf16<<<dim3(HS / 128, TOKS / 128), 256, 0, stream>>>(
      att, wot, out, TOKS, HS, HS);
}

// Round 5
// 337.307 us; speedup vs baseline: 10.5188x; 1.1776x over previous
//
#include <hip/hip_runtime.h>
#include <math.h>

#define TOKS 4096
#define HS   2048
#define QKV_N 3072
#define S_LEN 2048
#define NH   16
#define NKV  4
#define DH   128

typedef __attribute__((ext_vector_type(8))) short short8;
typedef __attribute__((ext_vector_type(4))) float f32x4;

static __device__ __forceinline__ unsigned short f2bf(float f) {
  unsigned u = __builtin_bit_cast(unsigned, f);
  u += 0x7fffu + ((u >> 16) & 1u);           // round-to-nearest-even
  return (unsigned short)(u >> 16);
}

// ---------------------------------------------------------------------------
// f32 -> bf16 elementwise, 8 elems/thread
// ---------------------------------------------------------------------------
__global__ __launch_bounds__(256)
void cvt_bf16(const float* __restrict__ in, unsigned short* __restrict__ out) {
  const size_t i = ((size_t)blockIdx.x * 256 + threadIdx.x) * 8;
  float4 a = *(const float4*)(in + i);
  float4 b = *(const float4*)(in + i + 4);
  short8 r;
  r[0] = f2bf(a.x); r[1] = f2bf(a.y); r[2] = f2bf(a.z); r[3] = f2bf(a.w);
  r[4] = f2bf(b.x); r[5] = f2bf(b.y); r[6] = f2bf(b.z); r[7] = f2bf(b.w);
  *(short8*)(out + i) = r;
}

// ---------------------------------------------------------------------------
// Transpose + cvt: out[c][r] = bf16(in[r][c]).  in rows have stride ldin.
// ---------------------------------------------------------------------------
__global__ __launch_bounds__(256)
void transpose_cvt(const float* __restrict__ in, unsigned short* __restrict__ out,
                   int R, int C, int ldin,
                   long in_z_hi, long in_z_lo, int z_mod, long out_z) {
  __shared__ float tile[32][33];
  const int z = blockIdx.z;
  in  += (size_t)(z / z_mod) * in_z_hi + (size_t)(z % z_mod) * in_z_lo;
  out += (size_t)z * out_z;
  const int r0 = blockIdx.x * 32, c0 = blockIdx.y * 32;
  const int tx = threadIdx.x & 31, ty = threadIdx.x >> 5;  // 32 x 8
  #pragma unroll
  for (int i = 0; i < 4; ++i)
    tile[ty + i * 8][tx] = in[(size_t)(r0 + ty + i * 8) * ldin + c0 + tx];
  __syncthreads();
  #pragma unroll
  for (int i = 0; i < 4; ++i)
    out[(size_t)(c0 + ty + i * 8) * R + r0 + tx] = f2bf(tile[tx][ty + i * 8]);
}

// ---------------------------------------------------------------------------
// RMSNorm + RoPE -> bf16 Qb [B][NH][S][DH] (pre-scaled by 1/sqrt(DH)),
// Kb [B][NKV][S][DH].
// ---------------------------------------------------------------------------
__global__ __launch_bounds__(64)
void norm_rope_cvt(const float* __restrict__ qkv, const int* __restrict__ positions,
                   const float* __restrict__ qw, const float* __restrict__ kw,
                   unsigned short* __restrict__ Qb, unsigned short* __restrict__ Kb) {
  const int tok  = blockIdx.x;
  const int slot = blockIdx.y;
  const int lane = threadIdx.x;
  const int b = tok >> 11, s = tok & 2047;

  const float* x; const float* wgt; unsigned short* outp; float scale;
  if (slot < NH) {
    x = qkv + (size_t)tok * QKV_N + slot * DH;  wgt = qw;
    outp = Qb + (((size_t)b * NH + slot) * S_LEN + s) * DH;
    scale = 0.08838834764831845f;
  } else {
    const int kh = slot - NH;
    x = qkv + (size_t)tok * QKV_N + NH * DH + kh * DH;  wgt = kw;
    outp = Kb + (((size_t)b * NKV + kh) * S_LEN + s) * DH;
    scale = 1.0f;
  }

  float x1 = x[lane], x2 = x[lane + 64];
  float ss = x1 * x1 + x2 * x2;
  #pragma unroll
  for (int o = 32; o > 0; o >>= 1) ss += __shfl_xor(ss, o, 64);
  const float rs = 1.0f / sqrtf(ss * (1.0f / 128.0f) + 1e-6f);
  const float n1 = x1 * rs * wgt[lane];
  const float n2 = x2 * rs * wgt[lane + 64];

  const float pos = (float)positions[tok];
  const float inv_freq = exp2f(-(float)lane * (13.287712379549449f / 64.0f));
  float sn, cs;
  sincosf(pos * inv_freq, &sn, &cs);

  outp[lane]      = f2bf((n1 * cs - n2 * sn) * scale);
  outp[lane + 64] = f2bf((n2 * cs + n1 * sn) * scale);
}

// ---------------------------------------------------------------------------
// bf16 MFMA GEMM (m97 structure): C[M][N] f32 = A[M][K] @ Bt[N][K]^T.
// ---------------------------------------------------------------------------
__global__ __launch_bounds__(256)
void gemm_bf16(const unsigned short* __restrict__ A, const unsigned short* __restrict__ Bt,
               float* __restrict__ C, int M, int N, int K) {
  __shared__ unsigned short As[128 * 32];
  __shared__ unsigned short Bs[128 * 32];
  const int t = threadIdx.x, w = t >> 6, l = t & 63;
  const int lm = l & 15, lr = l >> 4;
  const int bn = blockIdx.x * 128, bm = blockIdx.y * 128;
  const int wr = w >> 1, wc = w & 1;

  f32x4 acc[4][4];
  #pragma unroll
  for (int i = 0; i < 4; ++i)
    #pragma unroll
    for (int j = 0; j < 4; ++j) acc[i][j] = {0.f, 0.f, 0.f, 0.f};

  const int srow = l >> 2;
  const int scol = (l & 3) * 8;

  for (int k0 = 0; k0 < K; k0 += 32) {
    #pragma unroll
    for (int c = 0; c < 2; ++c) {
      const int rowA = (w + c * 4) * 16;
      const unsigned short* ga = A + (size_t)(bm + rowA + srow) * K + k0 + scol;
      const unsigned short* gb = Bt + (size_t)(bn + rowA + srow) * K + k0 + scol;
      __builtin_amdgcn_global_load_lds(
          (const __attribute__((address_space(1))) void*)ga,
          (__attribute__((address_space(3))) void*)(As + rowA * 32), 16, 0, 0);
      __builtin_amdgcn_global_load_lds(
          (const __attribute__((address_space(1))) void*)gb,
          (__attribute__((address_space(3))) void*)(Bs + rowA * 32), 16, 0, 0);
    }
    __syncthreads();

    short8 af[4], bf[4];
    #pragma unroll
    for (int mi = 0; mi < 4; ++mi)
      af[mi] = *(const short8*)(As + (wr * 64 + mi * 16 + lm) * 32 + lr * 8);
    #pragma unroll
    for (int ni = 0; ni < 4; ++ni)
      bf[ni] = *(const short8*)(Bs + (wc * 64 + ni * 16 + lm) * 32 + lr * 8);
    #pragma unroll
    for (int mi = 0; mi < 4; ++mi)
      #pragma unroll
      for (int ni = 0; ni < 4; ++ni)
        acc[mi][ni] = __builtin_amdgcn_mfma_f32_16x16x32_bf16(af[mi], bf[ni], acc[mi][ni], 0, 0, 0);
    __syncthreads();
  }

  #pragma unroll
  for (int mi = 0; mi < 4; ++mi)
    #pragma unroll
    for (int ni = 0; ni < 4; ++ni)
      #pragma unroll
      for (int j = 0; j < 4; ++j)
        C[(size_t)(bm + wr * 64 + mi * 16 + lr * 4 + j) * N + bn + wc * 64 + ni * 16 + lm] =
            acc[mi][ni][j];
}

// ---------------------------------------------------------------------------
// MFMA causal GQA flash attention v4.
// 4 waves/block, wave owns 32 q-rows, KVBLK=64, double-buffered LDS staging.
// qb = z ? x : 15-x  ->  co-resident block pair (same x,y; z=0/1) always
// sums to 34 tile-iters: per-CU load is uniform.  T13 defer-max (THR=8).
// ---------------------------------------------------------------------------
__global__ __launch_bounds__(256)
void attn_mfma(const unsigned short* __restrict__ Qb, const unsigned short* __restrict__ Kb,
               const unsigned short* __restrict__ Vt, unsigned short* __restrict__ att) {
  __shared__ unsigned short Ks_[2][64 * 128];   // 32 KB
  __shared__ unsigned short Vs_[2][128 * 64];   // 32 KB
  __shared__ unsigned short Pl[4][32 * 64];     // 16 KB

  const int x  = blockIdx.x;
  const int b  = blockIdx.z;
  const int qb = b ? x : 15 - x;                 // complementary pairing
  const int h  = blockIdx.y;
  const int kvh = h >> 2;
  const int t = threadIdx.x, w = t >> 6, l = t & 63;
  const int lm = l & 15, lr = l >> 4;
  const int row0 = qb * 128 + w * 32;            // wave's first q row

  const unsigned short* qbase = Qb + ((size_t)(b * NH + h)) * S_LEN * DH;
  const unsigned short* kbase = Kb + ((size_t)(b * NKV + kvh)) * S_LEN * DH;
  const unsigned short* vtbase = Vt + ((size_t)(b * NKV + kvh)) * DH * S_LEN;

  short8 qf[2][4];
  #pragma unroll
  for (int m = 0; m < 2; ++m)
    #pragma unroll
    for (int kc = 0; kc < 4; ++kc)
      qf[m][kc] = *(const short8*)(qbase + (size_t)(row0 + m * 16 + lm) * DH + kc * 32 + lr * 8);

  f32x4 o[2][8];
  #pragma unroll
  for (int m = 0; m < 2; ++m)
    #pragma unroll
    for (int ng = 0; ng < 8; ++ng) o[m][ng] = {0.f, 0.f, 0.f, 0.f};
  float m_run[2][4], l_run[2][4];
  #pragma unroll
  for (int m = 0; m < 2; ++m)
    #pragma unroll
    for (int j = 0; j < 4; ++j) { m_run[m][j] = -1e30f; l_run[m][j] = 0.f; }

  auto stage = [&](int bufi, int kb0) {
    #pragma unroll
    for (int i = 0; i < 4; ++i) {
      const int rk = w * 16 + i * 4 + (l >> 4);
      const unsigned short* gk =
          kbase + (size_t)(kb0 + rk) * DH + (((l & 15) ^ (rk & 7)) * 8);
      __builtin_amdgcn_global_load_lds(
          (const __attribute__((address_space(1))) void*)gk,
          (__attribute__((address_space(3))) void*)(&Ks_[bufi][(w * 16 + i * 4) * 128]),
          16, 0, 0);
      const int rv = w * 32 + i * 8 + (l >> 3);
      const unsigned short* gv =
          vtbase + (size_t)rv * S_LEN + kb0 + (((l & 7) ^ (rv & 7)) * 8);
      __builtin_amdgcn_global_load_lds(
          (const __attribute__((address_space(1))) void*)gv,
          (__attribute__((address_space(3))) void*)(&Vs_[bufi][(w * 32 + i * 8) * 64]),
          16, 0, 0);
    }
  };

  const int nkt = qb * 2 + 2;
  stage(0, 0);
  __syncthreads();

  for (int kt = 0; kt < nkt; ++kt) {
    const int kb0 = kt * 64;
    if (kt + 1 < nkt) stage((kt + 1) & 1, kb0 + 64);

    if (kb0 <= row0 + 31) {
      const unsigned short* Kc = Ks_[kt & 1];
      const unsigned short* Vc = Vs_[kt & 1];
      const int rsw = (lm & 7) << 3;

      // ---- S = Q K^T ----
      f32x4 s[2][4];
      #pragma unroll
      for (int m = 0; m < 2; ++m)
        #pragma unroll
        for (int n2 = 0; n2 < 4; ++n2) s[m][n2] = {0.f, 0.f, 0.f, 0.f};
      __builtin_amdgcn_s_setprio(1);
      #pragma unroll
      for (int n2 = 0; n2 < 4; ++n2) {
        short8 kf[4];
        #pragma unroll
        for (int kc = 0; kc < 4; ++kc)
          kf[kc] = *(const short8*)(Kc + (n2 * 16 + lm) * 128 + ((kc * 32 + lr * 8) ^ rsw));
        #pragma unroll
        for (int m = 0; m < 2; ++m)
          #pragma unroll
          for (int kc = 0; kc < 4; ++kc)
            s[m][n2] = __builtin_amdgcn_mfma_f32_16x16x32_bf16(qf[m][kc], kf[kc], s[m][n2], 0, 0, 0);
      }
      __builtin_amdgcn_s_setprio(0);

      // ---- causal mask ----
      if (kb0 + 63 > row0) {
        #pragma unroll
        for (int m = 0; m < 2; ++m) {
          const int qi = row0 + m * 16 + lr * 4;
          #pragma unroll
          for (int n2 = 0; n2 < 4; ++n2) {
            const int kvi = kb0 + n2 * 16 + lm;
            #pragma unroll
            for (int j = 0; j < 4; ++j)
              if (kvi > qi + j) s[m][n2][j] = -1e30f;
          }
        }
      }

      // ---- tile max (wave-parallel over the 16 kv-lanes) ----
      float mt[2][4];
      #pragma unroll
      for (int m = 0; m < 2; ++m)
        #pragma unroll
        for (int j = 0; j < 4; ++j) {
          float v = fmaxf(fmaxf(s[m][0][j], s[m][1][j]), fmaxf(s[m][2][j], s[m][3][j]));
          v = fmaxf(v, __shfl_xor(v, 1, 64));
          v = fmaxf(v, __shfl_xor(v, 2, 64));
          v = fmaxf(v, __shfl_xor(v, 4, 64));
          v = fmaxf(v, __shfl_xor(v, 8, 64));
          mt[m][j] = v;
        }

      // ---- T13 defer-max: rescale only when max grew by > 8 ----
      float need = -1e30f;
      #pragma unroll
      for (int m = 0; m < 2; ++m)
        #pragma unroll
        for (int j = 0; j < 4; ++j) need = fmaxf(need, mt[m][j] - m_run[m][j]);
      if (!__all(need <= 8.0f)) {
        #pragma unroll
        for (int m = 0; m < 2; ++m)
          #pragma unroll
          for (int j = 0; j < 4; ++j) {
            const float mn = fmaxf(m_run[m][j], mt[m][j]);
            const float al = __expf(m_run[m][j] - mn);
            m_run[m][j] = mn;
            l_run[m][j] *= al;
            #pragma unroll
            for (int ng = 0; ng < 8; ++ng) o[m][ng][j] *= al;
          }
      }

      // ---- P = exp(S - m_run), row sums, store P (swizzled) ----
      #pragma unroll
      for (int m = 0; m < 2; ++m)
        #pragma unroll
        for (int j = 0; j < 4; ++j) {
          const float mr = m_run[m][j];
          const float p0 = __expf(s[m][0][j] - mr);
          const float p1 = __expf(s[m][1][j] - mr);
          const float p2 = __expf(s[m][2][j] - mr);
          const float p3 = __expf(s[m][3][j] - mr);
          float sm = (p0 + p1) + (p2 + p3);
          sm += __shfl_xor(sm, 1, 64);
          sm += __shfl_xor(sm, 2, 64);
          sm += __shfl_xor(sm, 4, 64);
          sm += __shfl_xor(sm, 8, 64);
          l_run[m][j] += sm;
          const int prow = m * 16 + lr * 4 + j;
          unsigned short* Pw = &Pl[w][prow * 64];
          const int sw = (prow & 7) << 3;
          Pw[lm ^ sw]        = f2bf(p0);
          Pw[(16 + lm) ^ sw] = f2bf(p1);
          Pw[(32 + lm) ^ sw] = f2bf(p2);
          Pw[(48 + lm) ^ sw] = f2bf(p3);
        }
      __asm__ volatile("s_waitcnt lgkmcnt(0)" ::: "memory");

      // ---- O += P V ----
      short8 pf[2][2];
      #pragma unroll
      for (int m = 0; m < 2; ++m)
        #pragma unroll
        for (int k2 = 0; k2 < 2; ++k2)
          pf[m][k2] = *(const short8*)(&Pl[w][(m * 16 + lm) * 64 + ((k2 * 32 + lr * 8) ^ rsw)]);
      __builtin_amdgcn_s_setprio(1);
      #pragma unroll
      for (int ng = 0; ng < 8; ++ng) {
        const short8 vf0 = *(const short8*)(Vc + (ng * 16 + lm) * 64 + ((lr * 8) ^ rsw));
        const short8 vf1 = *(const short8*)(Vc + (ng * 16 + lm) * 64 + ((32 + lr * 8) ^ rsw));
        o[0][ng] = __builtin_amdgcn_mfma_f32_16x16x32_bf16(pf[0][0], vf0, o[0][ng], 0, 0, 0);
        o[1][ng] = __builtin_amdgcn_mfma_f32_16x16x32_bf16(pf[1][0], vf0, o[1][ng], 0, 0, 0);
        o[0][ng] = __builtin_amdgcn_mfma_f32_16x16x32_bf16(pf[0][1], vf1, o[0][ng], 0, 0, 0);
        o[1][ng] = __builtin_amdgcn_mfma_f32_16x16x32_bf16(pf[1][1], vf1, o[1][ng], 0, 0, 0);
      }
      __builtin_amdgcn_s_setprio(0);
    }
    __syncthreads();
  }

  // ---- epilogue ----
  #pragma unroll
  for (int m = 0; m < 2; ++m)
    #pragma unroll
    for (int j = 0; j < 4; ++j) {
      const float linv = 1.0f / l_run[m][j];
      unsigned short* ar =
          att + ((size_t)(b * S_LEN) + row0 + m * 16 + lr * 4 + j) * (NH * DH) + h * DH + lm;
      #pragma unroll
      for (int ng = 0; ng < 8; ++ng) ar[ng * 16] = f2bf(o[m][ng][j] * linv);
    }
}

// ---------------------------------------------------------------------------
extern "C" void kernel_launch(void* const* d_in, const int* in_sizes, int n_in,
                              void* d_out, int out_size, void* d_ws, size_t ws_size,
                              hipStream_t stream) {
  const int*   positions = (const int*)  d_in[0];
  const float* hidden    = (const float*)d_in[1];
  const float* w_qkv     = (const float*)d_in[2];
  const float* w_o       = (const float*)d_in[3];
  const float* q_norm_w  = (const float*)d_in[4];
  const float* k_norm_w  = (const float*)d_in[5];
  float* out = (float*)d_out;

  char* ws = (char*)d_ws;
  float*          qkv   = (float*)ws;
  unsigned short* att   = (unsigned short*)ws;                  // reuses dead qkv
  char* region = ws + (size_t)TOKS * QKV_N * 4;                 // +50,331,648
  unsigned short* hb    = (unsigned short*)region;              // dies after qkv GEMM
  unsigned short* Qb    = (unsigned short*)region;              // reuses hb
  unsigned short* wqkvt = (unsigned short*)(region + 16777216); // dies after qkv GEMM
  unsigned short* Kb    = (unsigned short*)(region + 16777216);
  unsigned short* Vt    = (unsigned short*)(region + 20971520);
  unsigned short* wot   = (unsigned short*)(region + 25165824);

  cvt_bf16<<<(TOKS * HS) / (256 * 8), 256, 0, stream>>>(hidden, hb);
  transpose_cvt<<<dim3(HS / 32, QKV_N / 32, 1), 256, 0, stream>>>(
      w_qkv, wqkvt, HS, QKV_N, QKV_N, 0, 0, 1, 0);
  gemm_bf16<<<dim3(QKV_N / 128, TOKS / 128), 256, 0, stream>>>(
      hb, wqkvt, qkv, TOKS, QKV_N, HS);
  norm_rope_cvt<<<dim3(TOKS, NH + NKV), 64, 0, stream>>>(
      qkv, positions, q_norm_w, k_norm_w, Qb, Kb);
  transpose_cvt<<<dim3(S_LEN / 32, DH / 32, 2 * NKV), 256, 0, stream>>>(
      qkv + (NH + NKV) * DH, Vt, S_LEN, DH, QKV_N,
      (long)S_LEN * QKV_N, DH, NKV, (long)DH * S_LEN);
  transpose_cvt<<<dim3(HS / 32, HS / 32, 1), 256, 0, stream>>>(
      w_o, wot, HS, HS, HS, 0, 0, 1, 0);
  attn_mfma<<<dim3(16, NH, 2), 256, 0, stream>>>(Qb, Kb, Vt, att);
  gemm_bf16<<<dim3(HS / 128, TOKS / 128), 256, 0, stream>>>(
      att, wot, out, TOKS, HS, HS);
}

// Round 6
// 294.795 us; speedup vs baseline: 12.0357x; 1.1442x over previous
//
#include <hip/hip_runtime.h>
#include <math.h>

#define TOKS 4096
#define HS   2048
#define QKV_N 3072
#define S_LEN 2048
#define NH   16
#define NKV  4
#define DH   128

typedef __attribute__((ext_vector_type(8))) short short8;
typedef __attribute__((ext_vector_type(4))) float f32x4;

static __device__ __forceinline__ unsigned short f2bf(float f) {
  unsigned u = __builtin_bit_cast(unsigned, f);
  u += 0x7fffu + ((u >> 16) & 1u);           // round-to-nearest-even
  return (unsigned short)(u >> 16);
}

// ---------------------------------------------------------------------------
// f32 -> bf16 elementwise, 8 elems/thread
// ---------------------------------------------------------------------------
__global__ __launch_bounds__(256)
void cvt_bf16(const float* __restrict__ in, unsigned short* __restrict__ out) {
  const size_t i = ((size_t)blockIdx.x * 256 + threadIdx.x) * 8;
  float4 a = *(const float4*)(in + i);
  float4 b = *(const float4*)(in + i + 4);
  short8 r;
  r[0] = f2bf(a.x); r[1] = f2bf(a.y); r[2] = f2bf(a.z); r[3] = f2bf(a.w);
  r[4] = f2bf(b.x); r[5] = f2bf(b.y); r[6] = f2bf(b.z); r[7] = f2bf(b.w);
  *(short8*)(out + i) = r;
}

// ---------------------------------------------------------------------------
// Transpose + cvt: out[c][r] = bf16(in[r][c]).  in rows have stride ldin.
// ---------------------------------------------------------------------------
__global__ __launch_bounds__(256)
void transpose_cvt(const float* __restrict__ in, unsigned short* __restrict__ out,
                   int R, int C, int ldin,
                   long in_z_hi, long in_z_lo, int z_mod, long out_z) {
  __shared__ float tile[32][33];
  const int z = blockIdx.z;
  in  += (size_t)(z / z_mod) * in_z_hi + (size_t)(z % z_mod) * in_z_lo;
  out += (size_t)z * out_z;
  const int r0 = blockIdx.x * 32, c0 = blockIdx.y * 32;
  const int tx = threadIdx.x & 31, ty = threadIdx.x >> 5;  // 32 x 8
  #pragma unroll
  for (int i = 0; i < 4; ++i)
    tile[ty + i * 8][tx] = in[(size_t)(r0 + ty + i * 8) * ldin + c0 + tx];
  __syncthreads();
  #pragma unroll
  for (int i = 0; i < 4; ++i)
    out[(size_t)(c0 + ty + i * 8) * R + r0 + tx] = f2bf(tile[tx][ty + i * 8]);
}

// ---------------------------------------------------------------------------
// RMSNorm + RoPE -> bf16 Qb [B][NH][S][DH] (pre-scaled by 1/sqrt(DH)),
// Kb [B][NKV][S][DH].
// ---------------------------------------------------------------------------
__global__ __launch_bounds__(64)
void norm_rope_cvt(const float* __restrict__ qkv, const int* __restrict__ positions,
                   const float* __restrict__ qw, const float* __restrict__ kw,
                   unsigned short* __restrict__ Qb, unsigned short* __restrict__ Kb) {
  const int tok  = blockIdx.x;
  const int slot = blockIdx.y;
  const int lane = threadIdx.x;
  const int b = tok >> 11, s = tok & 2047;

  const float* x; const float* wgt; unsigned short* outp; float scale;
  if (slot < NH) {
    x = qkv + (size_t)tok * QKV_N + slot * DH;  wgt = qw;
    outp = Qb + (((size_t)b * NH + slot) * S_LEN + s) * DH;
    scale = 0.08838834764831845f;
  } else {
    const int kh = slot - NH;
    x = qkv + (size_t)tok * QKV_N + NH * DH + kh * DH;  wgt = kw;
    outp = Kb + (((size_t)b * NKV + kh) * S_LEN + s) * DH;
    scale = 1.0f;
  }

  float x1 = x[lane], x2 = x[lane + 64];
  float ss = x1 * x1 + x2 * x2;
  #pragma unroll
  for (int o = 32; o > 0; o >>= 1) ss += __shfl_xor(ss, o, 64);
  const float rs = 1.0f / sqrtf(ss * (1.0f / 128.0f) + 1e-6f);
  const float n1 = x1 * rs * wgt[lane];
  const float n2 = x2 * rs * wgt[lane + 64];

  const float pos = (float)positions[tok];
  const float inv_freq = exp2f(-(float)lane * (13.287712379549449f / 64.0f));
  float sn, cs;
  sincosf(pos * inv_freq, &sn, &cs);

  outp[lane]      = f2bf((n1 * cs - n2 * sn) * scale);
  outp[lane + 64] = f2bf((n2 * cs + n1 * sn) * scale);
}

// ---------------------------------------------------------------------------
// bf16 MFMA GEMM (m97 structure): C[M][N] f32 = A[M][K] @ Bt[N][K]^T.
// ---------------------------------------------------------------------------
__global__ __launch_bounds__(256)
void gemm_bf16(const unsigned short* __restrict__ A, const unsigned short* __restrict__ Bt,
               float* __restrict__ C, int M, int N, int K) {
  __shared__ unsigned short As[128 * 32];
  __shared__ unsigned short Bs[128 * 32];
  const int t = threadIdx.x, w = t >> 6, l = t & 63;
  const int lm = l & 15, lr = l >> 4;
  const int bn = blockIdx.x * 128, bm = blockIdx.y * 128;
  const int wr = w >> 1, wc = w & 1;

  f32x4 acc[4][4];
  #pragma unroll
  for (int i = 0; i < 4; ++i)
    #pragma unroll
    for (int j = 0; j < 4; ++j) acc[i][j] = {0.f, 0.f, 0.f, 0.f};

  const int srow = l >> 2;
  const int scol = (l & 3) * 8;

  for (int k0 = 0; k0 < K; k0 += 32) {
    #pragma unroll
    for (int c = 0; c < 2; ++c) {
      const int rowA = (w + c * 4) * 16;
      const unsigned short* ga = A + (size_t)(bm + rowA + srow) * K + k0 + scol;
      const unsigned short* gb = Bt + (size_t)(bn + rowA + srow) * K + k0 + scol;
      __builtin_amdgcn_global_load_lds(
          (const __attribute__((address_space(1))) void*)ga,
          (__attribute__((address_space(3))) void*)(As + rowA * 32), 16, 0, 0);
      __builtin_amdgcn_global_load_lds(
          (const __attribute__((address_space(1))) void*)gb,
          (__attribute__((address_space(3))) void*)(Bs + rowA * 32), 16, 0, 0);
    }
    __syncthreads();

    short8 af[4], bf[4];
    #pragma unroll
    for (int mi = 0; mi < 4; ++mi)
      af[mi] = *(const short8*)(As + (wr * 64 + mi * 16 + lm) * 32 + lr * 8);
    #pragma unroll
    for (int ni = 0; ni < 4; ++ni)
      bf[ni] = *(const short8*)(Bs + (wc * 64 + ni * 16 + lm) * 32 + lr * 8);
    #pragma unroll
    for (int mi = 0; mi < 4; ++mi)
      #pragma unroll
      for (int ni = 0; ni < 4; ++ni)
        acc[mi][ni] = __builtin_amdgcn_mfma_f32_16x16x32_bf16(af[mi], bf[ni], acc[mi][ni], 0, 0, 0);
    __syncthreads();
  }

  #pragma unroll
  for (int mi = 0; mi < 4; ++mi)
    #pragma unroll
    for (int ni = 0; ni < 4; ++ni)
      #pragma unroll
      for (int j = 0; j < 4; ++j)
        C[(size_t)(bm + wr * 64 + mi * 16 + lr * 4 + j) * N + bn + wc * 64 + ni * 16 + lm] =
            acc[mi][ni][j];
}

// ---------------------------------------------------------------------------
// MFMA causal GQA flash attention v5.
// Same structure as v4 (4 waves/block, 32 q-rows/wave, KVBLK=64, dbuf LDS,
// complementary z-pairing) but the per-iter softmax fast path has ZERO
// cross-lane ops: P = exp(S - m_stale) with lane-local overflow check
// (__all), row-sum l via an extra ones-MFMA. Rare slow path rescales by
// 1/rowmax(P) for rows whose P exceeded e^8.
// ---------------------------------------------------------------------------
#define M_INIT 12.0f
#define P_CAP  2981.0f     // e^8

__global__ __launch_bounds__(256, 3)
void attn_mfma(const unsigned short* __restrict__ Qb, const unsigned short* __restrict__ Kb,
               const unsigned short* __restrict__ Vt, unsigned short* __restrict__ att) {
  __shared__ unsigned short Ks_[2][64 * 128];   // 32 KB
  __shared__ unsigned short Vs_[2][128 * 64];   // 32 KB
  __shared__ unsigned short Pl[4][32 * 64];     // 16 KB

  const int x  = blockIdx.x;
  const int b  = blockIdx.z;
  const int qb = b ? x : 15 - x;                 // complementary pairing
  const int h  = blockIdx.y;
  const int kvh = h >> 2;
  const int t = threadIdx.x, w = t >> 6, l = t & 63;
  const int lm = l & 15, lr = l >> 4;
  const int row0 = qb * 128 + w * 32;            // wave's first q row

  const unsigned short* qbase = Qb + ((size_t)(b * NH + h)) * S_LEN * DH;
  const unsigned short* kbase = Kb + ((size_t)(b * NKV + kvh)) * S_LEN * DH;
  const unsigned short* vtbase = Vt + ((size_t)(b * NKV + kvh)) * DH * S_LEN;

  short8 qf[2][4];
  #pragma unroll
  for (int m = 0; m < 2; ++m)
    #pragma unroll
    for (int kc = 0; kc < 4; ++kc)
      qf[m][kc] = *(const short8*)(qbase + (size_t)(row0 + m * 16 + lm) * DH + kc * 32 + lr * 8);

  short8 ones;
  #pragma unroll
  for (int i = 0; i < 8; ++i) ones[i] = (short)0x3F80;   // bf16 1.0

  f32x4 o[2][8];
  #pragma unroll
  for (int m = 0; m < 2; ++m)
    #pragma unroll
    for (int ng = 0; ng < 8; ++ng) o[m][ng] = {0.f, 0.f, 0.f, 0.f};
  f32x4 lacc[2];
  lacc[0] = {0.f, 0.f, 0.f, 0.f}; lacc[1] = {0.f, 0.f, 0.f, 0.f};
  float m_run[2][4];
  #pragma unroll
  for (int m = 0; m < 2; ++m)
    #pragma unroll
    for (int j = 0; j < 4; ++j) m_run[m][j] = M_INIT;

  auto stage = [&](int bufi, int kb0) {
    #pragma unroll
    for (int i = 0; i < 4; ++i) {
      const int rk = w * 16 + i * 4 + (l >> 4);
      const unsigned short* gk =
          kbase + (size_t)(kb0 + rk) * DH + (((l & 15) ^ (rk & 7)) * 8);
      __builtin_amdgcn_global_load_lds(
          (const __attribute__((address_space(1))) void*)gk,
          (__attribute__((address_space(3))) void*)(&Ks_[bufi][(w * 16 + i * 4) * 128]),
          16, 0, 0);
      const int rv = w * 32 + i * 8 + (l >> 3);
      const unsigned short* gv =
          vtbase + (size_t)rv * S_LEN + kb0 + (((l & 7) ^ (rv & 7)) * 8);
      __builtin_amdgcn_global_load_lds(
          (const __attribute__((address_space(1))) void*)gv,
          (__attribute__((address_space(3))) void*)(&Vs_[bufi][(w * 32 + i * 8) * 64]),
          16, 0, 0);
    }
  };

  const int nkt = qb * 2 + 2;
  stage(0, 0);
  __syncthreads();

  for (int kt = 0; kt < nkt; ++kt) {
    const int kb0 = kt * 64;
    if (kt + 1 < nkt) stage((kt + 1) & 1, kb0 + 64);

    if (kb0 <= row0 + 31) {
      const unsigned short* Kc = Ks_[kt & 1];
      const unsigned short* Vc = Vs_[kt & 1];
      const int rsw = (lm & 7) << 3;

      // ---- S = Q K^T ----
      f32x4 s[2][4];
      #pragma unroll
      for (int m = 0; m < 2; ++m)
        #pragma unroll
        for (int n2 = 0; n2 < 4; ++n2) s[m][n2] = {0.f, 0.f, 0.f, 0.f};
      __builtin_amdgcn_s_setprio(1);
      #pragma unroll
      for (int n2 = 0; n2 < 4; ++n2) {
        short8 kf[4];
        #pragma unroll
        for (int kc = 0; kc < 4; ++kc)
          kf[kc] = *(const short8*)(Kc + (n2 * 16 + lm) * 128 + ((kc * 32 + lr * 8) ^ rsw));
        #pragma unroll
        for (int m = 0; m < 2; ++m)
          #pragma unroll
          for (int kc = 0; kc < 4; ++kc)
            s[m][n2] = __builtin_amdgcn_mfma_f32_16x16x32_bf16(qf[m][kc], kf[kc], s[m][n2], 0, 0, 0);
      }
      __builtin_amdgcn_s_setprio(0);

      // ---- causal mask ----
      if (kb0 + 63 > row0) {
        #pragma unroll
        for (int m = 0; m < 2; ++m) {
          const int qi = row0 + m * 16 + lr * 4;
          #pragma unroll
          for (int n2 = 0; n2 < 4; ++n2) {
            const int kvi = kb0 + n2 * 16 + lm;
            #pragma unroll
            for (int j = 0; j < 4; ++j)
              if (kvi > qi + j) s[m][n2][j] = -1e30f;
          }
        }
      }

      // ---- fast softmax: P = exp(S - m_stale), in place; no cross-lane ----
      float pm = 0.f;
      #pragma unroll
      for (int m = 0; m < 2; ++m)
        #pragma unroll
        for (int n2 = 0; n2 < 4; ++n2)
          #pragma unroll
          for (int j = 0; j < 4; ++j) {
            const float p = __expf(s[m][n2][j] - m_run[m][j]);
            s[m][n2][j] = p;
            pm = fmaxf(pm, p);
          }

      if (!__all(pm <= P_CAP)) {
        // slow path (rare): per-row P-max via chains; rescale rows > e^8
        #pragma unroll
        for (int m = 0; m < 2; ++m)
          #pragma unroll
          for (int j = 0; j < 4; ++j) {
            float v = fmaxf(fmaxf(s[m][0][j], s[m][1][j]), fmaxf(s[m][2][j], s[m][3][j]));
            v = fmaxf(v, __shfl_xor(v, 1, 64));
            v = fmaxf(v, __shfl_xor(v, 2, 64));
            v = fmaxf(v, __shfl_xor(v, 4, 64));
            v = fmaxf(v, __shfl_xor(v, 8, 64));
            if (v > P_CAP) {
              const float al = 1.0f / v;            // = exp(m_old - m_new)
              m_run[m][j] += __logf(v);
              lacc[m][j] *= al;
              #pragma unroll
              for (int n2 = 0; n2 < 4; ++n2) s[m][n2][j] *= al;
              #pragma unroll
              for (int ng = 0; ng < 8; ++ng) o[m][ng][j] *= al;
            }
          }
      }

      // ---- store P (swizzled) ----
      #pragma unroll
      for (int m = 0; m < 2; ++m)
        #pragma unroll
        for (int j = 0; j < 4; ++j) {
          const int prow = m * 16 + lr * 4 + j;
          unsigned short* Pw = &Pl[w][prow * 64];
          const int sw = (prow & 7) << 3;
          Pw[lm ^ sw]        = f2bf(s[m][0][j]);
          Pw[(16 + lm) ^ sw] = f2bf(s[m][1][j]);
          Pw[(32 + lm) ^ sw] = f2bf(s[m][2][j]);
          Pw[(48 + lm) ^ sw] = f2bf(s[m][3][j]);
        }
      __asm__ volatile("s_waitcnt lgkmcnt(0)" ::: "memory");

      // ---- O += P V ;  l += P @ ones ----
      short8 pf[2][2];
      #pragma unroll
      for (int m = 0; m < 2; ++m)
        #pragma unroll
        for (int k2 = 0; k2 < 2; ++k2)
          pf[m][k2] = *(const short8*)(&Pl[w][(m * 16 + lm) * 64 + ((k2 * 32 + lr * 8) ^ rsw)]);
      __builtin_amdgcn_s_setprio(1);
      #pragma unroll
      for (int m = 0; m < 2; ++m)
        #pragma unroll
        for (int k2 = 0; k2 < 2; ++k2)
          lacc[m] = __builtin_amdgcn_mfma_f32_16x16x32_bf16(pf[m][k2], ones, lacc[m], 0, 0, 0);
      #pragma unroll
      for (int ng = 0; ng < 8; ++ng) {
        const short8 vf0 = *(const short8*)(Vc + (ng * 16 + lm) * 64 + ((lr * 8) ^ rsw));
        const short8 vf1 = *(const short8*)(Vc + (ng * 16 + lm) * 64 + ((32 + lr * 8) ^ rsw));
        o[0][ng] = __builtin_amdgcn_mfma_f32_16x16x32_bf16(pf[0][0], vf0, o[0][ng], 0, 0, 0);
        o[1][ng] = __builtin_amdgcn_mfma_f32_16x16x32_bf16(pf[1][0], vf0, o[1][ng], 0, 0, 0);
        o[0][ng] = __builtin_amdgcn_mfma_f32_16x16x32_bf16(pf[0][1], vf1, o[0][ng], 0, 0, 0);
        o[1][ng] = __builtin_amdgcn_mfma_f32_16x16x32_bf16(pf[1][1], vf1, o[1][ng], 0, 0, 0);
      }
      __builtin_amdgcn_s_setprio(0);
    }
    __syncthreads();
  }

  // ---- epilogue ----
  #pragma unroll
  for (int m = 0; m < 2; ++m)
    #pragma unroll
    for (int j = 0; j < 4; ++j) {
      const float linv = 1.0f / lacc[m][j];
      unsigned short* ar =
          att + ((size_t)(b * S_LEN) + row0 + m * 16 + lr * 4 + j) * (NH * DH) + h * DH + lm;
      #pragma unroll
      for (int ng = 0; ng < 8; ++ng) ar[ng * 16] = f2bf(o[m][ng][j] * linv);
    }
}

// ---------------------------------------------------------------------------
extern "C" void kernel_launch(void* const* d_in, const int* in_sizes, int n_in,
                              void* d_out, int out_size, void* d_ws, size_t ws_size,
                              hipStream_t stream) {
  const int*   positions = (const int*)  d_in[0];
  const float* hidden    = (const float*)d_in[1];
  const float* w_qkv     = (const float*)d_in[2];
  const float* w_o       = (const float*)d_in[3];
  const float* q_norm_w  = (const float*)d_in[4];
  const float* k_norm_w  = (const float*)d_in[5];
  float* out = (float*)d_out;

  char* ws = (char*)d_ws;
  float*          qkv   = (float*)ws;
  unsigned short* att   = (unsigned short*)ws;                  // reuses dead qkv
  char* region = ws + (size_t)TOKS * QKV_N * 4;                 // +50,331,648
  unsigned short* hb    = (unsigned short*)region;              // dies after qkv GEMM
  unsigned short* Qb    = (unsigned short*)region;              // reuses hb
  unsigned short* wqkvt = (unsigned short*)(region + 16777216); // dies after qkv GEMM
  unsigned short* Kb    = (unsigned short*)(region + 16777216);
  unsigned short* Vt    = (unsigned short*)(region + 20971520);
  unsigned short* wot   = (unsigned short*)(region + 25165824);

  cvt_bf16<<<(TOKS * HS) / (256 * 8), 256, 0, stream>>>(hidden, hb);
  transpose_cvt<<<dim3(HS / 32, QKV_N / 32, 1), 256, 0, stream>>>(
      w_qkv, wqkvt, HS, QKV_N, QKV_N, 0, 0, 1, 0);
  gemm_bf16<<<dim3(QKV_N / 128, TOKS / 128), 256, 0, stream>>>(
      hb, wqkvt, qkv, TOKS, QKV_N, HS);
  norm_rope_cvt<<<dim3(TOKS, NH + NKV), 64, 0, stream>>>(
      qkv, positions, q_norm_w, k_norm_w, Qb, Kb);
  transpose_cvt<<<dim3(S_LEN / 32, DH / 32, 2 * NKV), 256, 0, stream>>>(
      qkv + (NH + NKV) * DH, Vt, S_LEN, DH, QKV_N,
      (long)S_LEN * QKV_N, DH, NKV, (long)DH * S_LEN);
  transpose_cvt<<<dim3(HS / 32, HS / 32, 1), 256, 0, stream>>>(
      w_o, wot, HS, HS, HS, 0, 0, 1, 0);
  attn_mfma<<<dim3(16, NH, 2), 256, 0, stream>>>(Qb, Kb, Vt, att);
  gemm_bf16<<<dim3(HS / 128, TOKS / 128), 256, 0, stream>>>(
      att, wot, out, TOKS, HS, HS);
}

// Round 8
// 284.398 us; speedup vs baseline: 12.4757x; 1.0366x over previous
//
#include <hip/hip_runtime.h>
#include <math.h>

#define TOKS 4096
#define HS   2048
#define QKV_N 3072
#define S_LEN 2048
#define NH   16
#define NKV  4
#define DH   128

typedef __attribute__((ext_vector_type(8))) short short8;
typedef __attribute__((ext_vector_type(4))) float f32x4;

static __device__ __forceinline__ unsigned short f2bf(float f) {
  unsigned u = __builtin_bit_cast(unsigned, f);
  u += 0x7fffu + ((u >> 16) & 1u);           // round-to-nearest-even
  return (unsigned short)(u >> 16);
}

// ---------------------------------------------------------------------------
// f32 -> bf16 elementwise, 8 elems/thread
// ---------------------------------------------------------------------------
__global__ __launch_bounds__(256)
void cvt_bf16(const float* __restrict__ in, unsigned short* __restrict__ out) {
  const size_t i = ((size_t)blockIdx.x * 256 + threadIdx.x) * 8;
  float4 a = *(const float4*)(in + i);
  float4 b = *(const float4*)(in + i + 4);
  short8 r;
  r[0] = f2bf(a.x); r[1] = f2bf(a.y); r[2] = f2bf(a.z); r[3] = f2bf(a.w);
  r[4] = f2bf(b.x); r[5] = f2bf(b.y); r[6] = f2bf(b.z); r[7] = f2bf(b.w);
  *(short8*)(out + i) = r;
}

// ---------------------------------------------------------------------------
// Transpose + cvt: out[c][r] = bf16(in[r][c]).  in rows have stride ldin.
// ---------------------------------------------------------------------------
__global__ __launch_bounds__(256)
void transpose_cvt(const float* __restrict__ in, unsigned short* __restrict__ out,
                   int R, int C, int ldin,
                   long in_z_hi, long in_z_lo, int z_mod, long out_z) {
  __shared__ float tile[32][33];
  const int z = blockIdx.z;
  in  += (size_t)(z / z_mod) * in_z_hi + (size_t)(z % z_mod) * in_z_lo;
  out += (size_t)z * out_z;
  const int r0 = blockIdx.x * 32, c0 = blockIdx.y * 32;
  const int tx = threadIdx.x & 31, ty = threadIdx.x >> 5;  // 32 x 8
  #pragma unroll
  for (int i = 0; i < 4; ++i)
    tile[ty + i * 8][tx] = in[(size_t)(r0 + ty + i * 8) * ldin + c0 + tx];
  __syncthreads();
  #pragma unroll
  for (int i = 0; i < 4; ++i)
    out[(size_t)(c0 + ty + i * 8) * R + r0 + tx] = f2bf(tile[tx][ty + i * 8]);
}

// ---------------------------------------------------------------------------
// RMSNorm + RoPE -> bf16 Qb [B][NH][S][DH] (pre-scaled by 1/sqrt(DH)),
// Kb [B][NKV][S][DH].
// ---------------------------------------------------------------------------
__global__ __launch_bounds__(64)
void norm_rope_cvt(const float* __restrict__ qkv, const int* __restrict__ positions,
                   const float* __restrict__ qw, const float* __restrict__ kw,
                   unsigned short* __restrict__ Qb, unsigned short* __restrict__ Kb) {
  const int tok  = blockIdx.x;
  const int slot = blockIdx.y;
  const int lane = threadIdx.x;
  const int b = tok >> 11, s = tok & 2047;

  const float* x; const float* wgt; unsigned short* outp; float scale;
  if (slot < NH) {
    x = qkv + (size_t)tok * QKV_N + slot * DH;  wgt = qw;
    outp = Qb + (((size_t)b * NH + slot) * S_LEN + s) * DH;
    scale = 0.08838834764831845f;
  } else {
    const int kh = slot - NH;
    x = qkv + (size_t)tok * QKV_N + NH * DH + kh * DH;  wgt = kw;
    outp = Kb + (((size_t)b * NKV + kh) * S_LEN + s) * DH;
    scale = 1.0f;
  }

  float x1 = x[lane], x2 = x[lane + 64];
  float ss = x1 * x1 + x2 * x2;
  #pragma unroll
  for (int o = 32; o > 0; o >>= 1) ss += __shfl_xor(ss, o, 64);
  const float rs = 1.0f / sqrtf(ss * (1.0f / 128.0f) + 1e-6f);
  const float n1 = x1 * rs * wgt[lane];
  const float n2 = x2 * rs * wgt[lane + 64];

  const float pos = (float)positions[tok];
  const float inv_freq = exp2f(-(float)lane * (13.287712379549449f / 64.0f));
  float sn, cs;
  sincosf(pos * inv_freq, &sn, &cs);

  outp[lane]      = f2bf((n1 * cs - n2 * sn) * scale);
  outp[lane + 64] = f2bf((n2 * cs + n1 * sn) * scale);
}

// ---------------------------------------------------------------------------
// 8-phase 256x256 bf16 MFMA GEMM (T2+T3+T4+T5): C[M][N] f32 = A @ Bt^T.
// BK=64, 512 threads (8 waves, 2Mx4N), per-wave 128x64 output, 128KB LDS
// (2 dbuf x [256][64] per operand), XOR (row&7) swizzle both-sides,
// counted vmcnt (4) at phases 4/8, setprio around MFMA clusters.
// Requires K % 128 == 0, M % 256 == 0, N % 256 == 0.
// ---------------------------------------------------------------------------
__global__ __launch_bounds__(512, 2)
void gemm256(const unsigned short* __restrict__ A, const unsigned short* __restrict__ Bt,
             float* __restrict__ C, int M, int N, int K) {
  __shared__ __align__(16) unsigned short LA[2][256 * 64];   // 64 KB
  __shared__ __align__(16) unsigned short LB[2][256 * 64];   // 64 KB

  const int t = threadIdx.x, w = t >> 6, l = t & 63;
  const int lm = l & 15, lr = l >> 4;
  const int wr = w >> 2, wc = w & 3;              // 2 x 4 wave grid
  const int bn = blockIdx.x * 256, bm = blockIdx.y * 256;
  const int nkt = K >> 6;                         // 64-wide K tiles

  f32x4 acc[8][4];
  #pragma unroll
  for (int mi = 0; mi < 8; ++mi)
    #pragma unroll
    for (int ni = 0; ni < 4; ++ni) acc[mi][ni] = {0.f, 0.f, 0.f, 0.f};

  // Stage one 128-row half of a [256][64] operand tile. Linear LDS dest
  // (global_load_lds), k-slot pre-swizzled by (row&7) in the SOURCE.
  auto stage = [&](const unsigned short* G, int gbase, unsigned short* Lb,
                   int half, int kt) {
    if (kt >= nkt) return;
    const int k0 = kt << 6;
    #pragma unroll
    for (int r = 0; r < 2; ++r) {
      const int row  = half * 128 + r * 64 + (t >> 3);
      const int slot = (t & 7) ^ (row & 7);
      const unsigned short* src = G + (size_t)(gbase + row) * K + k0 + slot * 8;
      __builtin_amdgcn_global_load_lds(
          (const __attribute__((address_space(1))) void*)src,
          (__attribute__((address_space(3))) void*)(Lb + (half * 128 + r * 64 + w * 8) * 64),
          16, 0, 0);
    }
  };

  // Prologue: B(0), A(0), B(1); tile0 complete (vmcnt(4) leaves B(1) in flight)
  stage(Bt, bn, &LB[0][0], 0, 0); stage(Bt, bn, &LB[0][0], 1, 0);
  stage(A,  bm, &LA[0][0], 0, 0); stage(A,  bm, &LA[0][0], 1, 0);
  stage(Bt, bn, &LB[1][0], 0, 1); stage(Bt, bn, &LB[1][0], 1, 1);
  asm volatile("s_waitcnt vmcnt(4)" ::: "memory");
  __builtin_amdgcn_s_barrier();

  const int niter = nkt >> 1;
  for (int i = 0; i < niter; ++i) {
    const int t0 = i * 2;
    short8 bfr[4][2];
    #pragma unroll
    for (int p = 0; p < 8; ++p) {
      const int buf = p >> 2, q = p & 3;
      const unsigned short* La = &LA[buf][0];
      const unsigned short* Lb = &LB[buf][0];

      // ---- ds-reads for this phase ----
      if (q == 0) {
        #pragma unroll
        for (int ni = 0; ni < 4; ++ni)
          #pragma unroll
          for (int ks = 0; ks < 2; ++ks) {
            const int row = wc * 64 + ni * 16 + lm;
            bfr[ni][ks] = *(const short8*)(Lb + row * 64 +
                                           ((ks * 32 + lr * 8) ^ ((row & 7) << 3)));
          }
      }
      short8 af[2][2];
      #pragma unroll
      for (int mi2 = 0; mi2 < 2; ++mi2)
        #pragma unroll
        for (int ks = 0; ks < 2; ++ks) {
          const int row = wr * 128 + (q * 2 + mi2) * 16 + lm;
          af[mi2][ks] = *(const short8*)(La + row * 64 +
                                         ((ks * 32 + lr * 8) ^ ((row & 7) << 3)));
        }

      // ---- stage plan: region written >=1 phase after its last read ----
      switch (p) {
        case 0: stage(A,  bm, &LA[1][0], 0, t0 + 1); break;
        case 1: stage(A,  bm, &LA[1][0], 1, t0 + 1); break;
        case 2: stage(Bt, bn, &LB[0][0], 0, t0 + 2); break;
        case 3: stage(Bt, bn, &LB[0][0], 1, t0 + 2); break;
        case 4: stage(A,  bm, &LA[0][0], 0, t0 + 2); break;
        case 5: stage(A,  bm, &LA[0][0], 1, t0 + 2); break;
        case 6: stage(Bt, bn, &LB[1][0], 0, t0 + 3); break;
        case 7: stage(Bt, bn, &LB[1][0], 1, t0 + 3); break;
      }

      __builtin_amdgcn_s_barrier();
      asm volatile("s_waitcnt lgkmcnt(0)" ::: "memory");
      __builtin_amdgcn_sched_barrier(0);

      __builtin_amdgcn_s_setprio(1);
      #pragma unroll
      for (int mi2 = 0; mi2 < 2; ++mi2)
        #pragma unroll
        for (int ni = 0; ni < 4; ++ni)
          #pragma unroll
          for (int ks = 0; ks < 2; ++ks)
            acc[q * 2 + mi2][ni] = __builtin_amdgcn_mfma_f32_16x16x32_bf16(
                af[mi2][ks], bfr[ni][ks], acc[q * 2 + mi2][ni], 0, 0, 0);
      __builtin_amdgcn_s_setprio(0);

      if (q == 3) {
        // counted in steady state; full drain on the last iter (its skipped
        // stages would make vmcnt(4) vacuous -> race)
        if (i == niter - 1) asm volatile("s_waitcnt vmcnt(0)" ::: "memory");
        else                asm volatile("s_waitcnt vmcnt(4)" ::: "memory");
      }
      __builtin_amdgcn_s_barrier();
    }
  }

  // ---- epilogue: C/D layout col=lane&15, row=(lane>>4)*4+j ----
  #pragma unroll
  for (int mi = 0; mi < 8; ++mi)
    #pragma unroll
    for (int ni = 0; ni < 4; ++ni)
      #pragma unroll
      for (int j = 0; j < 4; ++j)
        C[(size_t)(bm + wr * 128 + mi * 16 + lr * 4 + j) * N + bn + wc * 64 + ni * 16 + lm] =
            acc[mi][ni][j];
}

// ---------------------------------------------------------------------------
// MFMA causal GQA flash attention v5 (unchanged from R6).
// ---------------------------------------------------------------------------
#define M_INIT 12.0f
#define P_CAP  2981.0f     // e^8

__global__ __launch_bounds__(256, 3)
void attn_mfma(const unsigned short* __restrict__ Qb, const unsigned short* __restrict__ Kb,
               const unsigned short* __restrict__ Vt, unsigned short* __restrict__ att) {
  __shared__ unsigned short Ks_[2][64 * 128];   // 32 KB
  __shared__ unsigned short Vs_[2][128 * 64];   // 32 KB
  __shared__ unsigned short Pl[4][32 * 64];     // 16 KB

  const int x  = blockIdx.x;
  const int b  = blockIdx.z;
  const int qb = b ? x : 15 - x;                 // complementary pairing
  const int h  = blockIdx.y;
  const int kvh = h >> 2;
  const int t = threadIdx.x, w = t >> 6, l = t & 63;
  const int lm = l & 15, lr = l >> 4;
  const int row0 = qb * 128 + w * 32;            // wave's first q row

  const unsigned short* qbase = Qb + ((size_t)(b * NH + h)) * S_LEN * DH;
  const unsigned short* kbase = Kb + ((size_t)(b * NKV + kvh)) * S_LEN * DH;
  const unsigned short* vtbase = Vt + ((size_t)(b * NKV + kvh)) * DH * S_LEN;

  short8 qf[2][4];
  #pragma unroll
  for (int m = 0; m < 2; ++m)
    #pragma unroll
    for (int kc = 0; kc < 4; ++kc)
      qf[m][kc] = *(const short8*)(qbase + (size_t)(row0 + m * 16 + lm) * DH + kc * 32 + lr * 8);

  short8 ones;
  #pragma unroll
  for (int i = 0; i < 8; ++i) ones[i] = (short)0x3F80;   // bf16 1.0

  f32x4 o[2][8];
  #pragma unroll
  for (int m = 0; m < 2; ++m)
    #pragma unroll
    for (int ng = 0; ng < 8; ++ng) o[m][ng] = {0.f, 0.f, 0.f, 0.f};
  f32x4 lacc[2];
  lacc[0] = {0.f, 0.f, 0.f, 0.f}; lacc[1] = {0.f, 0.f, 0.f, 0.f};
  float m_run[2][4];
  #pragma unroll
  for (int m = 0; m < 2; ++m)
    #pragma unroll
    for (int j = 0; j < 4; ++j) m_run[m][j] = M_INIT;

  auto stage = [&](int bufi, int kb0) {
    #pragma unroll
    for (int i = 0; i < 4; ++i) {
      const int rk = w * 16 + i * 4 + (l >> 4);
      const unsigned short* gk =
          kbase + (size_t)(kb0 + rk) * DH + (((l & 15) ^ (rk & 7)) * 8);
      __builtin_amdgcn_global_load_lds(
          (const __attribute__((address_space(1))) void*)gk,
          (__attribute__((address_space(3))) void*)(&Ks_[bufi][(w * 16 + i * 4) * 128]),
          16, 0, 0);
      const int rv = w * 32 + i * 8 + (l >> 3);
      const unsigned short* gv =
          vtbase + (size_t)rv * S_LEN + kb0 + (((l & 7) ^ (rv & 7)) * 8);
      __builtin_amdgcn_global_load_lds(
          (const __attribute__((address_space(1))) void*)gv,
          (__attribute__((address_space(3))) void*)(&Vs_[bufi][(w * 32 + i * 8) * 64]),
          16, 0, 0);
    }
  };

  const int nkt = qb * 2 + 2;
  stage(0, 0);
  __syncthreads();

  for (int kt = 0; kt < nkt; ++kt) {
    const int kb0 = kt * 64;
    if (kt + 1 < nkt) stage((kt + 1) & 1, kb0 + 64);

    if (kb0 <= row0 + 31) {
      const unsigned short* Kc = Ks_[kt & 1];
      const unsigned short* Vc = Vs_[kt & 1];
      const int rsw = (lm & 7) << 3;

      // ---- S = Q K^T ----
      f32x4 s[2][4];
      #pragma unroll
      for (int m = 0; m < 2; ++m)
        #pragma unroll
        for (int n2 = 0; n2 < 4; ++n2) s[m][n2] = {0.f, 0.f, 0.f, 0.f};
      __builtin_amdgcn_s_setprio(1);
      #pragma unroll
      for (int n2 = 0; n2 < 4; ++n2) {
        short8 kf[4];
        #pragma unroll
        for (int kc = 0; kc < 4; ++kc)
          kf[kc] = *(const short8*)(Kc + (n2 * 16 + lm) * 128 + ((kc * 32 + lr * 8) ^ rsw));
        #pragma unroll
        for (int m = 0; m < 2; ++m)
          #pragma unroll
          for (int kc = 0; kc < 4; ++kc)
            s[m][n2] = __builtin_amdgcn_mfma_f32_16x16x32_bf16(qf[m][kc], kf[kc], s[m][n2], 0, 0, 0);
      }
      __builtin_amdgcn_s_setprio(0);

      // ---- causal mask ----
      if (kb0 + 63 > row0) {
        #pragma unroll
        for (int m = 0; m < 2; ++m) {
          const int qi = row0 + m * 16 + lr * 4;
          #pragma unroll
          for (int n2 = 0; n2 < 4; ++n2) {
            const int kvi = kb0 + n2 * 16 + lm;
            #pragma unroll
            for (int j = 0; j < 4; ++j)
              if (kvi > qi + j) s[m][n2][j] = -1e30f;
          }
        }
      }

      // ---- fast softmax: P = exp(S - m_stale), in place; no cross-lane ----
      float pm = 0.f;
      #pragma unroll
      for (int m = 0; m < 2; ++m)
        #pragma unroll
        for (int n2 = 0; n2 < 4; ++n2)
          #pragma unroll
          for (int j = 0; j < 4; ++j) {
            const float p = __expf(s[m][n2][j] - m_run[m][j]);
            s[m][n2][j] = p;
            pm = fmaxf(pm, p);
          }

      if (!__all(pm <= P_CAP)) {
        // slow path (rare): per-row P-max via chains; rescale rows > e^8
        #pragma unroll
        for (int m = 0; m < 2; ++m)
          #pragma unroll
          for (int j = 0; j < 4; ++j) {
            float v = fmaxf(fmaxf(s[m][0][j], s[m][1][j]), fmaxf(s[m][2][j], s[m][3][j]));
            v = fmaxf(v, __shfl_xor(v, 1, 64));
            v = fmaxf(v, __shfl_xor(v, 2, 64));
            v = fmaxf(v, __shfl_xor(v, 4, 64));
            v = fmaxf(v, __shfl_xor(v, 8, 64));
            if (v > P_CAP) {
              const float al = 1.0f / v;            // = exp(m_old - m_new)
              m_run[m][j] += __logf(v);
              lacc[m][j] *= al;
              #pragma unroll
              for (int n2 = 0; n2 < 4; ++n2) s[m][n2][j] *= al;
              #pragma unroll
              for (int ng = 0; ng < 8; ++ng) o[m][ng][j] *= al;
            }
          }
      }

      // ---- store P (swizzled) ----
      #pragma unroll
      for (int m = 0; m < 2; ++m)
        #pragma unroll
        for (int j = 0; j < 4; ++j) {
          const int prow = m * 16 + lr * 4 + j;
          unsigned short* Pw = &Pl[w][prow * 64];
          const int sw = (prow & 7) << 3;
          Pw[lm ^ sw]        = f2bf(s[m][0][j]);
          Pw[(16 + lm) ^ sw] = f2bf(s[m][1][j]);
          Pw[(32 + lm) ^ sw] = f2bf(s[m][2][j]);
          Pw[(48 + lm) ^ sw] = f2bf(s[m][3][j]);
        }
      __asm__ volatile("s_waitcnt lgkmcnt(0)" ::: "memory");

      // ---- O += P V ;  l += P @ ones ----
      short8 pf[2][2];
      #pragma unroll
      for (int m = 0; m < 2; ++m)
        #pragma unroll
        for (int k2 = 0; k2 < 2; ++k2)
          pf[m][k2] = *(const short8*)(&Pl[w][(m * 16 + lm) * 64 + ((k2 * 32 + lr * 8) ^ rsw)]);
      __builtin_amdgcn_s_setprio(1);
      #pragma unroll
      for (int m = 0; m < 2; ++m)
        #pragma unroll
        for (int k2 = 0; k2 < 2; ++k2)
          lacc[m] = __builtin_amdgcn_mfma_f32_16x16x32_bf16(pf[m][k2], ones, lacc[m], 0, 0, 0);
      #pragma unroll
      for (int ng = 0; ng < 8; ++ng) {
        const short8 vf0 = *(const short8*)(Vc + (ng * 16 + lm) * 64 + ((lr * 8) ^ rsw));
        const short8 vf1 = *(const short8*)(Vc + (ng * 16 + lm) * 64 + ((32 + lr * 8) ^ rsw));
        o[0][ng] = __builtin_amdgcn_mfma_f32_16x16x32_bf16(pf[0][0], vf0, o[0][ng], 0, 0, 0);
        o[1][ng] = __builtin_amdgcn_mfma_f32_16x16x32_bf16(pf[1][0], vf0, o[1][ng], 0, 0, 0);
        o[0][ng] = __builtin_amdgcn_mfma_f32_16x16x32_bf16(pf[0][1], vf1, o[0][ng], 0, 0, 0);
        o[1][ng] = __builtin_amdgcn_mfma_f32_16x16x32_bf16(pf[1][1], vf1, o[1][ng], 0, 0, 0);
      }
      __builtin_amdgcn_s_setprio(0);
    }
    __syncthreads();
  }

  // ---- epilogue ----
  #pragma unroll
  for (int m = 0; m < 2; ++m)
    #pragma unroll
    for (int j = 0; j < 4; ++j) {
      const float linv = 1.0f / lacc[m][j];
      unsigned short* ar =
          att + ((size_t)(b * S_LEN) + row0 + m * 16 + lr * 4 + j) * (NH * DH) + h * DH + lm;
      #pragma unroll
      for (int ng = 0; ng < 8; ++ng) ar[ng * 16] = f2bf(o[m][ng][j] * linv);
    }
}

// ---------------------------------------------------------------------------
extern "C" void kernel_launch(void* const* d_in, const int* in_sizes, int n_in,
                              void* d_out, int out_size, void* d_ws, size_t ws_size,
                              hipStream_t stream) {
  const int*   positions = (const int*)  d_in[0];
  const float* hidden    = (const float*)d_in[1];
  const float* w_qkv     = (const float*)d_in[2];
  const float* w_o       = (const float*)d_in[3];
  const float* q_norm_w  = (const float*)d_in[4];
  const float* k_norm_w  = (const float*)d_in[5];
  float* out = (float*)d_out;

  char* ws = (char*)d_ws;
  float*          qkv   = (float*)ws;
  unsigned short* att   = (unsigned short*)ws;                  // reuses dead qkv
  char* region = ws + (size_t)TOKS * QKV_N * 4;                 // +50,331,648
  unsigned short* hb    = (unsigned short*)region;              // dies after qkv GEMM
  unsigned short* Qb    = (unsigned short*)region;              // reuses hb
  unsigned short* wqkvt = (unsigned short*)(region + 16777216); // dies after qkv GEMM
  unsigned short* Kb    = (unsigned short*)(region + 16777216);
  unsigned short* Vt    = (unsigned short*)(region + 20971520);
  unsigned short* wot   = (unsigned short*)(region + 25165824);

  cvt_bf16<<<(TOKS * HS) / (256 * 8), 256, 0, stream>>>(hidden, hb);
  transpose_cvt<<<dim3(HS / 32, QKV_N / 32, 1), 256, 0, stream>>>(
      w_qkv, wqkvt, HS, QKV_N, QKV_N, 0, 0, 1, 0);
  gemm256<<<dim3(QKV_N / 256, TOKS / 256), 512, 0, stream>>>(
      hb, wqkvt, qkv, TOKS, QKV_N, HS);
  norm_rope_cvt<<<dim3(TOKS, NH + NKV), 64, 0, stream>>>(
      qkv, positions, q_norm_w, k_norm_w, Qb, Kb);
  transpose_cvt<<<dim3(S_LEN / 32, DH / 32, 2 * NKV), 256, 0, stream>>>(
      qkv + (NH + NKV) * DH, Vt, S_LEN, DH, QKV_N,
      (long)S_LEN * QKV_N, DH, NKV, (long)DH * S_LEN);
  transpose_cvt<<<dim3(HS / 32, HS / 32, 1), 256, 0, stream>>>(
      w_o, wot, HS, HS, HS, 0, 0, 1, 0);
  attn_mfma<<<dim3(16, NH, 2), 256, 0, stream>>>(Qb, Kb, Vt, att);
  gemm256<<<dim3(HS / 256, TOKS / 256), 512, 0, stream>>>(
      att, wot, out, TOKS, HS, HS);
}